// Round 3
// baseline (1677.850 us; speedup 1.0000x reference)
//
#include <hip/hip_runtime.h>
#include <math.h>

#define BB 48
#define LL 512
#define DD 192
#define HH 6
#define DKK 32
#define HID 768
#define ROWS (BB * LL)
#define BLD ((size_t)ROWS * DD)
#define SCALE_ATT 0.17677669529663687f  // 1/sqrt(32)

typedef unsigned short ushort_t;
typedef unsigned int uint_t;
typedef __bf16 bf16x8 __attribute__((ext_vector_type(8)));
typedef float f32x4 __attribute__((ext_vector_type(4)));

__device__ __forceinline__ ushort_t f2bf(float f) {
  union { float f; uint_t u; } v; v.f = f;
  uint_t r = v.u + 0x7fffu + ((v.u >> 16) & 1u);   // round-to-nearest-even
  return (ushort_t)(r >> 16);
}
__device__ __forceinline__ float bflo(uint_t u) {
  union { uint_t u; float f; } v; v.u = u << 16; return v.f;
}
__device__ __forceinline__ float bfhi(uint_t u) {
  union { uint_t u; float f; } v; v.u = u & 0xffff0000u; return v.f;
}

// ---------------------------------------------------------------------------
// Pack weights: transpose to [N][K] bf16, concat QKV; concat QKV bias fp32.
// ---------------------------------------------------------------------------
__global__ __launch_bounds__(256) void pack_kernel(
    const float* __restrict__ wq, const float* __restrict__ wk,
    const float* __restrict__ wv, const float* __restrict__ wo,
    const float* __restrict__ w1, const float* __restrict__ w2,
    const float* __restrict__ bq, const float* __restrict__ bk,
    const float* __restrict__ bv,
    ushort_t* __restrict__ Wqkv, ushort_t* __restrict__ Wo,
    ushort_t* __restrict__ W1, ushort_t* __restrict__ W2,
    float* __restrict__ bqkv) {
  int i = blockIdx.x * 256 + threadIdx.x;
  if (i < 110592) {                       // Wqkv_t [576][192]
    int n2 = i / 192, k = i - n2 * 192;
    int part = n2 / 192, n = n2 - part * 192;
    const float* src = part == 0 ? wq : (part == 1 ? wk : wv);
    Wqkv[i] = f2bf(src[k * 192 + n]);
  } else if (i < 147456) {                // Wo_t [192][192]
    int j = i - 110592;
    int n = j / 192, k = j - n * 192;
    Wo[j] = f2bf(wo[k * 192 + n]);
  } else if (i < 294912) {                // W1_t [768][192]
    int j = i - 147456;
    int n = j / 192, k = j - n * 192;
    W1[j] = f2bf(w1[k * 768 + n]);
  } else if (i < 442368) {                // W2_t [192][768]
    int j = i - 294912;
    int n = j / 768, k = j - n * 768;
    W2[j] = f2bf(w2[k * 192 + n]);
  } else if (i < 442944) {                // bqkv [576]
    int j = i - 442368;
    bqkv[j] = j < 192 ? bq[j] : (j < 384 ? bk[j - 192] : bv[j - 384]);
  }
}

// ---------------------------------------------------------------------------
// Masked LayerNorm, dual-dtype output: outf (fp32) and/or outb (bf16).
// One wave per row; D=192 -> 3 elements/lane.
// ---------------------------------------------------------------------------
__global__ __launch_bounds__(64) void mln_kernel(
    const float* __restrict__ x, const float* __restrict__ res,
    const int* __restrict__ valid, const float* __restrict__ g,
    const float* __restrict__ beta, float* __restrict__ outf,
    ushort_t* __restrict__ outb) {
  int row = blockIdx.x;
  int lane = threadIdx.x;
  const float* xr = x + (size_t)row * DD;
  float v0 = xr[lane], v1 = xr[lane + 64], v2 = xr[lane + 128];
  if (res != nullptr) {
    const float* rr = res + (size_t)row * DD;
    v0 += rr[lane]; v1 += rr[lane + 64]; v2 += rr[lane + 128];
  }
  float s = v0 + v1 + v2;
#pragma unroll
  for (int off = 32; off; off >>= 1) s += __shfl_xor(s, off);
  float mu = s * (1.0f / 192.0f);
  float d0 = v0 - mu, d1 = v1 - mu, d2 = v2 - mu;
  float ss = d0 * d0 + d1 * d1 + d2 * d2;
#pragma unroll
  for (int off = 32; off; off >>= 1) ss += __shfl_xor(ss, off);
  float inv = rsqrtf(ss * (1.0f / 192.0f) + 1e-5f);
  float r0, r1, r2;
  if (valid[row]) {
    r0 = d0 * inv * g[lane]       + beta[lane];
    r1 = d1 * inv * g[lane + 64]  + beta[lane + 64];
    r2 = d2 * inv * g[lane + 128] + beta[lane + 128];
  } else {
    r0 = v0; r1 = v1; r2 = v2;
  }
  size_t o = (size_t)row * DD;
  if (outf != nullptr) {
    outf[o + lane] = r0; outf[o + lane + 64] = r1; outf[o + lane + 128] = r2;
  }
  if (outb != nullptr) {
    outb[o + lane] = f2bf(r0); outb[o + lane + 64] = f2bf(r1);
    outb[o + lane + 128] = f2bf(r2);
  }
}

// ---------------------------------------------------------------------------
// bf16 MFMA GEMM: C[M,N] = A[M,K](bf16) @ Wt[N,K]^T(bf16) + bias
// Block: 128 threads (2 waves), tile M=128 x N=64; wave-tile 64x64
// via 4x4 grid of 16x16x32 MFMA. LDS rows padded to 40 bf16 (2-way-free).
// Output: fp32 (Cf) or bf16 (Cb), optional exact GELU.
// ---------------------------------------------------------------------------
__global__ __launch_bounds__(128) void gemm_mfma_kernel(
    const ushort_t* __restrict__ A, const ushort_t* __restrict__ Wt,
    const float* __restrict__ bias, float* __restrict__ Cf,
    ushort_t* __restrict__ Cb, int M, int N, int K, int gelu) {
  __shared__ ushort_t As[128 * 40];
  __shared__ ushort_t Bs[64 * 40];
  int tid = threadIdx.x;
  int lane = tid & 63;
  int w = tid >> 6;
  int row0 = blockIdx.y * 128;
  int col0 = blockIdx.x * 64;
  int l15 = lane & 15;
  int kq = lane >> 4;

  f32x4 acc[4][4];
#pragma unroll
  for (int i = 0; i < 4; ++i)
#pragma unroll
    for (int j = 0; j < 4; ++j) acc[i][j] = (f32x4){0.f, 0.f, 0.f, 0.f};

  for (int k0 = 0; k0 < K; k0 += 32) {
    uint4 av[4], bv[2];
#pragma unroll
    for (int i = 0; i < 4; ++i) {
      int idx = tid + i * 128;
      int r = idx >> 2, qd = idx & 3;
      av[i] = *(const uint4*)(A + (size_t)(row0 + r) * K + k0 + qd * 8);
    }
#pragma unroll
    for (int i = 0; i < 2; ++i) {
      int idx = tid + i * 128;
      int n = idx >> 2, qd = idx & 3;
      bv[i] = *(const uint4*)(Wt + (size_t)(col0 + n) * K + k0 + qd * 8);
    }
    __syncthreads();
#pragma unroll
    for (int i = 0; i < 4; ++i) {
      int idx = tid + i * 128;
      int r = idx >> 2, qd = idx & 3;
      *(uint4*)(&As[r * 40 + qd * 8]) = av[i];
    }
#pragma unroll
    for (int i = 0; i < 2; ++i) {
      int idx = tid + i * 128;
      int n = idx >> 2, qd = idx & 3;
      *(uint4*)(&Bs[n * 40 + qd * 8]) = bv[i];
    }
    __syncthreads();

    bf16x8 af[4], bf[4];
#pragma unroll
    for (int mt = 0; mt < 4; ++mt)
      af[mt] = *(const bf16x8*)(&As[(w * 64 + mt * 16 + l15) * 40 + kq * 8]);
#pragma unroll
    for (int nt = 0; nt < 4; ++nt)
      bf[nt] = *(const bf16x8*)(&Bs[(nt * 16 + l15) * 40 + kq * 8]);
#pragma unroll
    for (int mt = 0; mt < 4; ++mt)
#pragma unroll
      for (int nt = 0; nt < 4; ++nt)
        acc[mt][nt] = __builtin_amdgcn_mfma_f32_16x16x32_bf16(
            af[mt], bf[nt], acc[mt][nt], 0, 0, 0);
  }

  // epilogue: C row = row0 + w*64 + mt*16 + (lane>>4)*4 + r, col = col0 + nt*16 + l15
  float bcol[4];
#pragma unroll
  for (int nt = 0; nt < 4; ++nt) bcol[nt] = bias[col0 + nt * 16 + l15];
#pragma unroll
  for (int mt = 0; mt < 4; ++mt) {
#pragma unroll
    for (int nt = 0; nt < 4; ++nt) {
      int col = col0 + nt * 16 + l15;
#pragma unroll
      for (int r = 0; r < 4; ++r) {
        int row = row0 + w * 64 + mt * 16 + kq * 4 + r;
        float x = acc[mt][nt][r] + bcol[nt];
        if (gelu) x = 0.5f * x * (1.0f + erff(x * 0.70710678118654752f));
        if (Cf != nullptr) Cf[(size_t)row * N + col] = x;
        else Cb[(size_t)row * N + col] = f2bf(x);
      }
    }
  }
}

// ---------------------------------------------------------------------------
// Flash attention, bf16 QKV input, bf16 output. 128 threads per wg,
// 2 queries per thread (256 queries per wg). K/V staged fp32 in LDS.
// Qbase: Q at col h*32; KVbase: K at 192+h*32, V at 384+h*32 (row stride 576).
// ---------------------------------------------------------------------------
__global__ __launch_bounds__(128) void attn_kernel(
    const ushort_t* __restrict__ Qbase, const ushort_t* __restrict__ KVbase,
    const int* __restrict__ validq, const int* __restrict__ validk,
    ushort_t* __restrict__ out) {
  int wg = blockIdx.x;
  int qhalf = wg & 1;
  int h = (wg >> 1) % HH;
  int batch = wg / (2 * HH);
  int tid = threadIdx.x;
  int qA = qhalf * 256 + tid;
  int qB = qA + 128;

  __shared__ float Ks[64][32];
  __shared__ float Vs[64][32];
  __shared__ int vks[64];

  // load queries (bf16 -> fp32)
  float qrA[32], qrB[32];
  size_t qoffA = (size_t)(batch * LL + qA) * 576 + h * DKK;
  size_t qoffB = (size_t)(batch * LL + qB) * 576 + h * DKK;
#pragma unroll
  for (int i = 0; i < 4; ++i) {
    uint4 u = *(const uint4*)(Qbase + qoffA + i * 8);
    qrA[i*8+0] = bflo(u.x); qrA[i*8+1] = bfhi(u.x);
    qrA[i*8+2] = bflo(u.y); qrA[i*8+3] = bfhi(u.y);
    qrA[i*8+4] = bflo(u.z); qrA[i*8+5] = bfhi(u.z);
    qrA[i*8+6] = bflo(u.w); qrA[i*8+7] = bfhi(u.w);
    uint4 v = *(const uint4*)(Qbase + qoffB + i * 8);
    qrB[i*8+0] = bflo(v.x); qrB[i*8+1] = bfhi(v.x);
    qrB[i*8+2] = bflo(v.y); qrB[i*8+3] = bfhi(v.y);
    qrB[i*8+4] = bflo(v.z); qrB[i*8+5] = bfhi(v.z);
    qrB[i*8+6] = bflo(v.w); qrB[i*8+7] = bfhi(v.w);
  }
  int vqA = validq[batch * LL + qA];
  int vqB = validq[batch * LL + qB];

  float mA = -1e30f, lA = 0.0f, mB = -1e30f, lB = 0.0f;
  float oA[32], oB[32];
#pragma unroll
  for (int d = 0; d < 32; ++d) { oA[d] = 0.0f; oB[d] = 0.0f; }

  int kcol = 192 + h * DKK;
  int vcol = 384 + h * DKK;

  for (int c = 0; c < LL; c += 64) {
    __syncthreads();
#pragma unroll
    for (int i = 0; i < 2; ++i) {
      int idx = tid + i * 128;
      int kk = idx >> 2, dq = idx & 3;
      size_t base = (size_t)(batch * LL + c + kk) * 576;
      uint4 ku = *(const uint4*)(KVbase + base + kcol + dq * 8);
      uint4 vu = *(const uint4*)(KVbase + base + vcol + dq * 8);
      float4 k0 = {bflo(ku.x), bfhi(ku.x), bflo(ku.y), bfhi(ku.y)};
      float4 k1 = {bflo(ku.z), bfhi(ku.z), bflo(ku.w), bfhi(ku.w)};
      float4 v0 = {bflo(vu.x), bfhi(vu.x), bflo(vu.y), bfhi(vu.y)};
      float4 v1 = {bflo(vu.z), bfhi(vu.z), bflo(vu.w), bfhi(vu.w)};
      *(float4*)(&Ks[kk][dq * 8])     = k0;
      *(float4*)(&Ks[kk][dq * 8 + 4]) = k1;
      *(float4*)(&Vs[kk][dq * 8])     = v0;
      *(float4*)(&Vs[kk][dq * 8 + 4]) = v1;
    }
    if (tid < 64) vks[tid] = validk[batch * LL + c + tid];
    __syncthreads();

    for (int kk = 0; kk < 64; ++kk) {
      float dA = 0.0f, dB = 0.0f;
#pragma unroll
      for (int d4 = 0; d4 < 8; ++d4) {
        float4 k4 = *(const float4*)(&Ks[kk][d4 * 4]);
        dA += qrA[d4*4+0]*k4.x + qrA[d4*4+1]*k4.y + qrA[d4*4+2]*k4.z + qrA[d4*4+3]*k4.w;
        dB += qrB[d4*4+0]*k4.x + qrB[d4*4+1]*k4.y + qrB[d4*4+2]*k4.z + qrB[d4*4+3]*k4.w;
      }
      int vk = vks[kk];
      float sA = (vqA && vk) ? dA * SCALE_ATT : -1e9f;
      float sB = (vqB && vk) ? dB * SCALE_ATT : -1e9f;
      if (sA > mA) {
        float al = __expf(mA - sA); lA *= al;
#pragma unroll
        for (int d = 0; d < 32; ++d) oA[d] *= al;
        mA = sA;
      }
      if (sB > mB) {
        float al = __expf(mB - sB); lB *= al;
#pragma unroll
        for (int d = 0; d < 32; ++d) oB[d] *= al;
        mB = sB;
      }
      float pA = __expf(sA - mA); lA += pA;
      float pB = __expf(sB - mB); lB += pB;
#pragma unroll
      for (int d4 = 0; d4 < 8; ++d4) {
        float4 v4 = *(const float4*)(&Vs[kk][d4 * 4]);
        oA[d4*4+0] += pA * v4.x; oA[d4*4+1] += pA * v4.y;
        oA[d4*4+2] += pA * v4.z; oA[d4*4+3] += pA * v4.w;
        oB[d4*4+0] += pB * v4.x; oB[d4*4+1] += pB * v4.y;
        oB[d4*4+2] += pB * v4.z; oB[d4*4+3] += pB * v4.w;
      }
    }
  }
  float iA = 1.0f / lA, iB = 1.0f / lB;
  size_t orA = (size_t)(batch * LL + qA) * DD + h * DKK;
  size_t orB = (size_t)(batch * LL + qB) * DD + h * DKK;
#pragma unroll
  for (int i = 0; i < 4; ++i) {
    uint4 u;
    u.x = (uint_t)f2bf(oA[i*8+0]*iA) | ((uint_t)f2bf(oA[i*8+1]*iA) << 16);
    u.y = (uint_t)f2bf(oA[i*8+2]*iA) | ((uint_t)f2bf(oA[i*8+3]*iA) << 16);
    u.z = (uint_t)f2bf(oA[i*8+4]*iA) | ((uint_t)f2bf(oA[i*8+5]*iA) << 16);
    u.w = (uint_t)f2bf(oA[i*8+6]*iA) | ((uint_t)f2bf(oA[i*8+7]*iA) << 16);
    *(uint4*)(out + orA + i * 8) = u;
    uint4 v;
    v.x = (uint_t)f2bf(oB[i*8+0]*iB) | ((uint_t)f2bf(oB[i*8+1]*iB) << 16);
    v.y = (uint_t)f2bf(oB[i*8+2]*iB) | ((uint_t)f2bf(oB[i*8+3]*iB) << 16);
    v.z = (uint_t)f2bf(oB[i*8+4]*iB) | ((uint_t)f2bf(oB[i*8+5]*iB) << 16);
    v.w = (uint_t)f2bf(oB[i*8+6]*iB) | ((uint_t)f2bf(oB[i*8+7]*iB) << 16);
    *(uint4*)(out + orB + i * 8) = v;
  }
}

// ---------------------------------------------------------------------------
extern "C" void kernel_launch(void* const* d_in, const int* in_sizes, int n_in,
                              void* d_out, int out_size, void* d_ws, size_t ws_size,
                              hipStream_t stream) {
  const float* x_a = (const float*)d_in[0];
  const float* x_b = (const float*)d_in[1];
  const int* valid_a = (const int*)d_in[2];
  const int* valid_b = (const int*)d_in[3];
  const float* ln_a_g = (const float*)d_in[4];
  const float* ln_a_b = (const float*)d_in[5];
  const float* ln_b_g = (const float*)d_in[6];
  const float* ln_b_b = (const float*)d_in[7];
  const float* ln_oa_g = (const float*)d_in[8];
  const float* ln_oa_b = (const float*)d_in[9];
  const float* ln_ob_g = (const float*)d_in[10];
  const float* ln_ob_b = (const float*)d_in[11];
  const float* wq = (const float*)d_in[12];
  const float* bq = (const float*)d_in[13];
  const float* wk = (const float*)d_in[14];
  const float* bk = (const float*)d_in[15];
  const float* wv = (const float*)d_in[16];
  const float* bv = (const float*)d_in[17];
  const float* wo = (const float*)d_in[18];
  const float* bo = (const float*)d_in[19];
  const float* fln_g = (const float*)d_in[20];
  const float* fln_b = (const float*)d_in[21];
  const float* flno_g = (const float*)d_in[22];
  const float* flno_b = (const float*)d_in[23];
  const float* w1 = (const float*)d_in[24];
  const float* b1 = (const float*)d_in[25];
  const float* w2 = (const float*)d_in[26];
  const float* b2 = (const float*)d_in[27];

  char* wsb = (char*)d_ws;
  ushort_t* QKVa = (ushort_t*)(wsb);                 // [ROWS,576] bf16
  ushort_t* QKVb = (ushort_t*)(wsb + 28311552);      // [ROWS,576] bf16
  ushort_t* Hbf  = (ushort_t*)(wsb);                 // [ROWS,768] bf16 (reuses QKV)
  ushort_t* lnAb = (ushort_t*)(wsb + 56623104);      // [ROWS,192] bf16 (also FFN ln)
  ushort_t* lnBb = (ushort_t*)(wsb + 66060288);      // [ROWS,192] bf16
  ushort_t* attO = (ushort_t*)(wsb + 75497472);      // [ROWS,192] bf16
  float*    tmp  = (float*)(wsb + 84934656);         // [ROWS,192] fp32
  ushort_t* Wqkv = (ushort_t*)(wsb + 103809024);     // [576][192]
  ushort_t* Wo_t = Wqkv + 110592;                    // [192][192]
  ushort_t* W1_t = Wo_t + 36864;                     // [768][192]
  ushort_t* W2_t = W1_t + 147456;                    // [192][768]
  float*    bqkv = (float*)(W2_t + 147456);          // [576]

  float* out_a = (float*)d_out;
  float* out_b = (float*)d_out + BLD;

  dim3 b128(128), b64(64), b256(256);
  dim3 gQKV(576 / 64, ROWS / 128);
  dim3 gD(DD / 64, ROWS / 128);
  dim3 gH(HID / 64, ROWS / 128);
  dim3 gAttn(BB * HH * 2);
  dim3 gMln(ROWS);

  hipLaunchKernelGGL(pack_kernel, dim3(1731), b256, 0, stream,
                     wq, wk, wv, wo, w1, w2, bq, bk, bv,
                     Wqkv, Wo_t, W1_t, W2_t, bqkv);

  // pre-LN -> bf16
  hipLaunchKernelGGL(mln_kernel, gMln, b64, 0, stream,
                     x_a, nullptr, valid_a, ln_a_g, ln_a_b, (float*)nullptr, lnAb);
  hipLaunchKernelGGL(mln_kernel, gMln, b64, 0, stream,
                     x_b, nullptr, valid_b, ln_b_g, ln_b_b, (float*)nullptr, lnBb);

  // fused QKV per source
  hipLaunchKernelGGL(gemm_mfma_kernel, gQKV, b128, 0, stream,
                     lnAb, Wqkv, bqkv, (float*)nullptr, QKVa, ROWS, 576, DD, 0);
  hipLaunchKernelGGL(gemm_mfma_kernel, gQKV, b128, 0, stream,
                     lnBb, Wqkv, bqkv, (float*)nullptr, QKVb, ROWS, 576, DD, 0);

  // side A: Q from a, K/V from b
  hipLaunchKernelGGL(attn_kernel, gAttn, b128, 0, stream,
                     QKVa, QKVb, valid_a, valid_b, attO);
  hipLaunchKernelGGL(gemm_mfma_kernel, gD, b128, 0, stream,
                     attO, Wo_t, bo, tmp, (ushort_t*)nullptr, ROWS, DD, DD, 0);
  hipLaunchKernelGGL(mln_kernel, gMln, b64, 0, stream,
                     tmp, x_a, valid_a, ln_oa_g, ln_oa_b, out_a, (ushort_t*)nullptr);

  // side B: Q from b, K/V from a
  hipLaunchKernelGGL(attn_kernel, gAttn, b128, 0, stream,
                     QKVb, QKVa, valid_b, valid_a, attO);
  hipLaunchKernelGGL(gemm_mfma_kernel, gD, b128, 0, stream,
                     attO, Wo_t, bo, tmp, (ushort_t*)nullptr, ROWS, DD, DD, 0);
  hipLaunchKernelGGL(mln_kernel, gMln, b64, 0, stream,
                     tmp, x_b, valid_b, ln_ob_g, ln_ob_b, out_b, (ushort_t*)nullptr);

  // FFN side A (QKV buffers now free -> Hbf)
  hipLaunchKernelGGL(mln_kernel, gMln, b64, 0, stream,
                     out_a, nullptr, valid_a, fln_g, fln_b, (float*)nullptr, lnAb);
  hipLaunchKernelGGL(gemm_mfma_kernel, gH, b128, 0, stream,
                     lnAb, W1_t, b1, (float*)nullptr, Hbf, ROWS, HID, DD, 1);
  hipLaunchKernelGGL(gemm_mfma_kernel, gD, b128, 0, stream,
                     Hbf, W2_t, b2, tmp, (ushort_t*)nullptr, ROWS, DD, HID, 0);
  hipLaunchKernelGGL(mln_kernel, gMln, b64, 0, stream,
                     out_a, tmp, valid_a, flno_g, flno_b, out_a, (ushort_t*)nullptr);

  // FFN side B
  hipLaunchKernelGGL(mln_kernel, gMln, b64, 0, stream,
                     out_b, nullptr, valid_b, fln_g, fln_b, (float*)nullptr, lnAb);
  hipLaunchKernelGGL(gemm_mfma_kernel, gH, b128, 0, stream,
                     lnAb, W1_t, b1, (float*)nullptr, Hbf, ROWS, HID, DD, 1);
  hipLaunchKernelGGL(gemm_mfma_kernel, gD, b128, 0, stream,
                     Hbf, W2_t, b2, tmp, (ushort_t*)nullptr, ROWS, DD, HID, 0);
  hipLaunchKernelGGL(mln_kernel, gMln, b64, 0, stream,
                     out_b, tmp, valid_b, flno_g, flno_b, out_b, (ushort_t*)nullptr);
}

// Round 5
// 785.250 us; speedup vs baseline: 2.1367x; 2.1367x over previous
//
#include <hip/hip_runtime.h>
#include <math.h>

#define BB 48
#define LL 512
#define DD 192
#define HH 6
#define DKK 32
#define HID 768
#define ROWS (BB * LL)
#define BLD ((size_t)ROWS * DD)
#define SCALE_ATT 0.17677669529663687f  // 1/sqrt(32)

typedef unsigned short ushort_t;
typedef unsigned int uint_t;
typedef __bf16 bf16x8 __attribute__((ext_vector_type(8)));
typedef float f32x4 __attribute__((ext_vector_type(4)));

union U4BF8 { uint4 u; bf16x8 b; };   // bit-cast helper

__device__ __forceinline__ ushort_t f2bf(float f) {
  union { float f; uint_t u; } v; v.f = f;
  uint_t r = v.u + 0x7fffu + ((v.u >> 16) & 1u);   // round-to-nearest-even
  return (ushort_t)(r >> 16);
}
__device__ __forceinline__ float bf2f(ushort_t u) {
  union { uint_t u; float f; } v; v.u = ((uint_t)u) << 16; return v.f;
}

// ---------------------------------------------------------------------------
// Pack weights: transpose to [N][K] bf16, concat QKV; concat QKV bias fp32.
// ---------------------------------------------------------------------------
__global__ __launch_bounds__(256) void pack_kernel(
    const float* __restrict__ wq, const float* __restrict__ wk,
    const float* __restrict__ wv, const float* __restrict__ wo,
    const float* __restrict__ w1, const float* __restrict__ w2,
    const float* __restrict__ bq, const float* __restrict__ bk,
    const float* __restrict__ bv,
    ushort_t* __restrict__ Wqkv, ushort_t* __restrict__ Wo,
    ushort_t* __restrict__ W1, ushort_t* __restrict__ W2,
    float* __restrict__ bqkv) {
  int i = blockIdx.x * 256 + threadIdx.x;
  if (i < 110592) {                       // Wqkv_t [576][192]
    int n2 = i / 192, k = i - n2 * 192;
    int part = n2 / 192, n = n2 - part * 192;
    const float* src = part == 0 ? wq : (part == 1 ? wk : wv);
    Wqkv[i] = f2bf(src[k * 192 + n]);
  } else if (i < 147456) {                // Wo_t [192][192]
    int j = i - 110592;
    int n = j / 192, k = j - n * 192;
    Wo[j] = f2bf(wo[k * 192 + n]);
  } else if (i < 294912) {                // W1_t [768][192]
    int j = i - 147456;
    int n = j / 192, k = j - n * 192;
    W1[j] = f2bf(w1[k * 768 + n]);
  } else if (i < 442368) {                // W2_t [192][768]
    int j = i - 294912;
    int n = j / 768, k = j - n * 768;
    W2[j] = f2bf(w2[k * 192 + n]);
  } else if (i < 442944) {                // bqkv [576]
    int j = i - 442368;
    bqkv[j] = j < 192 ? bq[j] : (j < 384 ? bk[j - 192] : bv[j - 384]);
  }
}

// ---------------------------------------------------------------------------
// Masked LayerNorm, dual-dtype output: outf (fp32) and/or outb (bf16).
// ---------------------------------------------------------------------------
__global__ __launch_bounds__(64) void mln_kernel(
    const float* __restrict__ x, const float* __restrict__ res,
    const int* __restrict__ valid, const float* __restrict__ g,
    const float* __restrict__ beta, float* __restrict__ outf,
    ushort_t* __restrict__ outb) {
  int row = blockIdx.x;
  int lane = threadIdx.x;
  const float* xr = x + (size_t)row * DD;
  float v0 = xr[lane], v1 = xr[lane + 64], v2 = xr[lane + 128];
  if (res != nullptr) {
    const float* rr = res + (size_t)row * DD;
    v0 += rr[lane]; v1 += rr[lane + 64]; v2 += rr[lane + 128];
  }
  float s = v0 + v1 + v2;
#pragma unroll
  for (int off = 32; off; off >>= 1) s += __shfl_xor(s, off);
  float mu = s * (1.0f / 192.0f);
  float d0 = v0 - mu, d1 = v1 - mu, d2 = v2 - mu;
  float ss = d0 * d0 + d1 * d1 + d2 * d2;
#pragma unroll
  for (int off = 32; off; off >>= 1) ss += __shfl_xor(ss, off);
  float inv = rsqrtf(ss * (1.0f / 192.0f) + 1e-5f);
  float r0, r1, r2;
  if (valid[row]) {
    r0 = d0 * inv * g[lane]       + beta[lane];
    r1 = d1 * inv * g[lane + 64]  + beta[lane + 64];
    r2 = d2 * inv * g[lane + 128] + beta[lane + 128];
  } else {
    r0 = v0; r1 = v1; r2 = v2;
  }
  size_t o = (size_t)row * DD;
  if (outf != nullptr) {
    outf[o + lane] = r0; outf[o + lane + 64] = r1; outf[o + lane + 128] = r2;
  }
  if (outb != nullptr) {
    outb[o + lane] = f2bf(r0); outb[o + lane + 64] = f2bf(r1);
    outb[o + lane + 128] = f2bf(r2);
  }
}

// ---------------------------------------------------------------------------
// bf16 MFMA GEMM (validated in R3): C = A @ Wt^T + bias
// ---------------------------------------------------------------------------
__global__ __launch_bounds__(128) void gemm_mfma_kernel(
    const ushort_t* __restrict__ A, const ushort_t* __restrict__ Wt,
    const float* __restrict__ bias, float* __restrict__ Cf,
    ushort_t* __restrict__ Cb, int M, int N, int K, int gelu) {
  __shared__ ushort_t As[128 * 40];
  __shared__ ushort_t Bs[64 * 40];
  int tid = threadIdx.x;
  int lane = tid & 63;
  int w = tid >> 6;
  int row0 = blockIdx.y * 128;
  int col0 = blockIdx.x * 64;
  int l15 = lane & 15;
  int kq = lane >> 4;

  f32x4 acc[4][4];
#pragma unroll
  for (int i = 0; i < 4; ++i)
#pragma unroll
    for (int j = 0; j < 4; ++j) acc[i][j] = (f32x4){0.f, 0.f, 0.f, 0.f};

  for (int k0 = 0; k0 < K; k0 += 32) {
    uint4 av[4], bv[2];
#pragma unroll
    for (int i = 0; i < 4; ++i) {
      int idx = tid + i * 128;
      int r = idx >> 2, qd = idx & 3;
      av[i] = *(const uint4*)(A + (size_t)(row0 + r) * K + k0 + qd * 8);
    }
#pragma unroll
    for (int i = 0; i < 2; ++i) {
      int idx = tid + i * 128;
      int n = idx >> 2, qd = idx & 3;
      bv[i] = *(const uint4*)(Wt + (size_t)(col0 + n) * K + k0 + qd * 8);
    }
    __syncthreads();
#pragma unroll
    for (int i = 0; i < 4; ++i) {
      int idx = tid + i * 128;
      int r = idx >> 2, qd = idx & 3;
      *(uint4*)(&As[r * 40 + qd * 8]) = av[i];
    }
#pragma unroll
    for (int i = 0; i < 2; ++i) {
      int idx = tid + i * 128;
      int n = idx >> 2, qd = idx & 3;
      *(uint4*)(&Bs[n * 40 + qd * 8]) = bv[i];
    }
    __syncthreads();

    bf16x8 af[4], bf[4];
#pragma unroll
    for (int mt = 0; mt < 4; ++mt)
      af[mt] = *(const bf16x8*)(&As[(w * 64 + mt * 16 + l15) * 40 + kq * 8]);
#pragma unroll
    for (int nt = 0; nt < 4; ++nt)
      bf[nt] = *(const bf16x8*)(&Bs[(nt * 16 + l15) * 40 + kq * 8]);
#pragma unroll
    for (int mt = 0; mt < 4; ++mt)
#pragma unroll
      for (int nt = 0; nt < 4; ++nt)
        acc[mt][nt] = __builtin_amdgcn_mfma_f32_16x16x32_bf16(
            af[mt], bf[nt], acc[mt][nt], 0, 0, 0);
  }

  float bcol[4];
#pragma unroll
  for (int nt = 0; nt < 4; ++nt) bcol[nt] = bias[col0 + nt * 16 + l15];
#pragma unroll
  for (int mt = 0; mt < 4; ++mt) {
#pragma unroll
    for (int nt = 0; nt < 4; ++nt) {
      int col = col0 + nt * 16 + l15;
#pragma unroll
      for (int r = 0; r < 4; ++r) {
        int row = row0 + w * 64 + mt * 16 + kq * 4 + r;
        float x = acc[mt][nt][r] + bcol[nt];
        if (gelu) x = 0.5f * x * (1.0f + erff(x * 0.70710678118654752f));
        if (Cf != nullptr) Cf[(size_t)row * N + col] = x;
        else Cb[(size_t)row * N + col] = f2bf(x);
      }
    }
  }
}

// ---------------------------------------------------------------------------
// MFMA flash attention. wg = 256 threads (4 waves) = one (b, h, qtile of 128).
// Wave w owns 32 queries (2 x 16-row A-frags). Per 64-key chunk:
//   S = Q@K^T via 8 mfma_16x16x32_bf16 (Q/K frags direct from global, L1-hot)
//   mask+scale on C-frags; online softmax (16-lane shuffle reductions)
//   P (bf16) -> wave-private LDS -> A-frags;  V^T staged in LDS (lane->key
//   mapping: scatter writes cover all 32 banks, conflict-free)
//   O += P@V^T via 8 MFMAs.  Epilogue: out = O / l.
// ---------------------------------------------------------------------------
__global__ __launch_bounds__(256) void attn_mfma_kernel(
    const ushort_t* __restrict__ Qbase, const ushort_t* __restrict__ KVbase,
    const int* __restrict__ validq, const int* __restrict__ validk,
    ushort_t* __restrict__ out) {
  int wg = blockIdx.x;
  int qt = wg & 3;
  int h = (wg >> 2) % HH;
  int batch = wg / (4 * HH);
  int tid = threadIdx.x;
  int w = tid >> 6;
  int lane = tid & 63;
  int l15 = lane & 15;
  int kq = lane >> 4;

  __shared__ ushort_t VsT[32 * 72];        // [dim][key], stride 72
  __shared__ ushort_t Ps[4][32 * 72];      // per-wave P [q][key], stride 72

  int qbase = qt * 128 + w * 32;
  size_t rowQ = (size_t)batch * LL + qbase;

  // Q A-frags: A[m=l15][k=kq*8+j]
  U4BF8 qfrag[2];
#pragma unroll
  for (int qs = 0; qs < 2; ++qs)
    qfrag[qs].u = *(const uint4*)(Qbase + (rowQ + qs * 16 + l15) * 576 +
                                  h * DKK + kq * 8);

  int vq[2][4];
#pragma unroll
  for (int qs = 0; qs < 2; ++qs)
#pragma unroll
    for (int r = 0; r < 4; ++r)
      vq[qs][r] = validq[batch * LL + qbase + qs * 16 + kq * 4 + r];

  float mrow[2][4], lrow[2][4];
  f32x4 Oacc[2][2];
#pragma unroll
  for (int qs = 0; qs < 2; ++qs) {
#pragma unroll
    for (int r = 0; r < 4; ++r) { mrow[qs][r] = -1e30f; lrow[qs][r] = 0.0f; }
#pragma unroll
    for (int ds = 0; ds < 2; ++ds) Oacc[qs][ds] = (f32x4){0.f, 0.f, 0.f, 0.f};
  }

  for (int c = 0; c < LL; c += 64) {
    __syncthreads();   // previous chunk's VsT reads done
    // stage V^T: lane -> key (c+lane), wave -> dim quad (w*8..w*8+7)
    uint4 vv = *(const uint4*)(KVbase + ((size_t)batch * LL + c + lane) * 576 +
                               384 + h * DKK + w * 8);
    uint_t uu[4] = {vv.x, vv.y, vv.z, vv.w};
#pragma unroll
    for (int j = 0; j < 4; ++j) {
      VsT[(w * 8 + 2 * j) * 72 + lane]     = (ushort_t)(uu[j] & 0xffffu);
      VsT[(w * 8 + 2 * j + 1) * 72 + lane] = (ushort_t)(uu[j] >> 16);
    }
    __syncthreads();   // VsT ready

    // S frags: one MFMA per (qsub, ksub); K B-frags direct from global
    f32x4 S[2][4];
    int vk[4];
#pragma unroll
    for (int ks = 0; ks < 4; ++ks) {
      U4BF8 kf;
      kf.u = *(const uint4*)(KVbase +
          ((size_t)batch * LL + c + ks * 16 + l15) * 576 + 192 + h * DKK + kq * 8);
      vk[ks] = validk[batch * LL + c + ks * 16 + l15];
#pragma unroll
      for (int qs = 0; qs < 2; ++qs) {
        f32x4 z = (f32x4){0.f, 0.f, 0.f, 0.f};
        S[qs][ks] = __builtin_amdgcn_mfma_f32_16x16x32_bf16(
            qfrag[qs].b, kf.b, z, 0, 0, 0);
      }
    }

    // mask + scale; chunk row max
    float cm[2][4];
#pragma unroll
    for (int qs = 0; qs < 2; ++qs)
#pragma unroll
      for (int r = 0; r < 4; ++r) {
        float mx = -1e30f;
#pragma unroll
        for (int ks = 0; ks < 4; ++ks) {
          float x = (vq[qs][r] && vk[ks]) ? S[qs][ks][r] * SCALE_ATT : -1e9f;
          S[qs][ks][r] = x;
          mx = fmaxf(mx, x);
        }
        cm[qs][r] = mx;
      }
#pragma unroll
    for (int qs = 0; qs < 2; ++qs)
#pragma unroll
      for (int r = 0; r < 4; ++r) {
        float mx = cm[qs][r];
#pragma unroll
        for (int off = 1; off < 16; off <<= 1) mx = fmaxf(mx, __shfl_xor(mx, off));
        float mn = fmaxf(mrow[qs][r], mx);
        float al = __expf(mrow[qs][r] - mn);
        mrow[qs][r] = mn;
        lrow[qs][r] *= al;
#pragma unroll
        for (int ds = 0; ds < 2; ++ds) Oacc[qs][ds][r] *= al;
      }

    // P = exp(S - m) -> bf16; rowsum of rounded P; store to wave-private LDS
#pragma unroll
    for (int qs = 0; qs < 2; ++qs) {
      float psum[4] = {0.f, 0.f, 0.f, 0.f};
#pragma unroll
      for (int ks = 0; ks < 4; ++ks)
#pragma unroll
        for (int r = 0; r < 4; ++r) {
          float p = __expf(S[qs][ks][r] - mrow[qs][r]);
          ushort_t pb = f2bf(p);
          psum[r] += bf2f(pb);
          Ps[w][(qs * 16 + kq * 4 + r) * 72 + ks * 16 + l15] = pb;
        }
#pragma unroll
      for (int r = 0; r < 4; ++r) {
        float sm = psum[r];
#pragma unroll
        for (int off = 1; off < 16; off <<= 1) sm += __shfl_xor(sm, off);
        lrow[qs][r] += sm;
      }
    }

    // PV: O[q][d] += P[q][k] * V^T[d][k]   (wave-private P: no barrier)
#pragma unroll
    for (int kh = 0; kh < 2; ++kh) {
      bf16x8 pf[2], vf[2];
#pragma unroll
      for (int qs = 0; qs < 2; ++qs)
        pf[qs] = *(const bf16x8*)(&Ps[w][(qs * 16 + l15) * 72 + kh * 32 + kq * 8]);
#pragma unroll
      for (int ds = 0; ds < 2; ++ds)
        vf[ds] = *(const bf16x8*)(&VsT[(ds * 16 + l15) * 72 + kh * 32 + kq * 8]);
#pragma unroll
      for (int qs = 0; qs < 2; ++qs)
#pragma unroll
        for (int ds = 0; ds < 2; ++ds)
          Oacc[qs][ds] = __builtin_amdgcn_mfma_f32_16x16x32_bf16(
              pf[qs], vf[ds], Oacc[qs][ds], 0, 0, 0);
    }
  }

  // epilogue: out = O / l
#pragma unroll
  for (int qs = 0; qs < 2; ++qs)
#pragma unroll
    for (int ds = 0; ds < 2; ++ds)
#pragma unroll
      for (int r = 0; r < 4; ++r) {
        int q = qbase + qs * 16 + kq * 4 + r;
        out[((size_t)batch * LL + q) * DD + h * DKK + ds * 16 + l15] =
            f2bf(Oacc[qs][ds][r] / lrow[qs][r]);
      }
}

// ---------------------------------------------------------------------------
extern "C" void kernel_launch(void* const* d_in, const int* in_sizes, int n_in,
                              void* d_out, int out_size, void* d_ws, size_t ws_size,
                              hipStream_t stream) {
  const float* x_a = (const float*)d_in[0];
  const float* x_b = (const float*)d_in[1];
  const int* valid_a = (const int*)d_in[2];
  const int* valid_b = (const int*)d_in[3];
  const float* ln_a_g = (const float*)d_in[4];
  const float* ln_a_b = (const float*)d_in[5];
  const float* ln_b_g = (const float*)d_in[6];
  const float* ln_b_b = (const float*)d_in[7];
  const float* ln_oa_g = (const float*)d_in[8];
  const float* ln_oa_b = (const float*)d_in[9];
  const float* ln_ob_g = (const float*)d_in[10];
  const float* ln_ob_b = (const float*)d_in[11];
  const float* wq = (const float*)d_in[12];
  const float* bq = (const float*)d_in[13];
  const float* wk = (const float*)d_in[14];
  const float* bk = (const float*)d_in[15];
  const float* wv = (const float*)d_in[16];
  const float* bv = (const float*)d_in[17];
  const float* wo = (const float*)d_in[18];
  const float* bo = (const float*)d_in[19];
  const float* fln_g = (const float*)d_in[20];
  const float* fln_b = (const float*)d_in[21];
  const float* flno_g = (const float*)d_in[22];
  const float* flno_b = (const float*)d_in[23];
  const float* w1 = (const float*)d_in[24];
  const float* b1 = (const float*)d_in[25];
  const float* w2 = (const float*)d_in[26];
  const float* b2 = (const float*)d_in[27];

  char* wsb = (char*)d_ws;
  ushort_t* QKVa = (ushort_t*)(wsb);                 // [ROWS,576] bf16
  ushort_t* QKVb = (ushort_t*)(wsb + 28311552);      // [ROWS,576] bf16
  ushort_t* Hbf  = (ushort_t*)(wsb);                 // [ROWS,768] bf16 (reuses QKV)
  ushort_t* lnAb = (ushort_t*)(wsb + 56623104);      // [ROWS,192] bf16
  ushort_t* lnBb = (ushort_t*)(wsb + 66060288);      // [ROWS,192] bf16
  ushort_t* attO = (ushort_t*)(wsb + 75497472);      // [ROWS,192] bf16
  float*    tmp  = (float*)(wsb + 84934656);         // [ROWS,192] fp32
  ushort_t* Wqkv = (ushort_t*)(wsb + 103809024);     // [576][192]
  ushort_t* Wo_t = Wqkv + 110592;                    // [192][192]
  ushort_t* W1_t = Wo_t + 36864;                     // [768][192]
  ushort_t* W2_t = W1_t + 147456;                    // [192][768]
  float*    bqkv = (float*)(W2_t + 147456);          // [576]

  float* out_a = (float*)d_out;
  float* out_b = (float*)d_out + BLD;

  dim3 b128(128), b64(64), b256(256);
  dim3 gQKV(576 / 64, ROWS / 128);
  dim3 gD(DD / 64, ROWS / 128);
  dim3 gH(HID / 64, ROWS / 128);
  dim3 gAttn(BB * HH * 4);   // 1152 wgs x 256 threads
  dim3 gMln(ROWS);

  hipLaunchKernelGGL(pack_kernel, dim3(1731), b256, 0, stream,
                     wq, wk, wv, wo, w1, w2, bq, bk, bv,
                     Wqkv, Wo_t, W1_t, W2_t, bqkv);

  // pre-LN -> bf16
  hipLaunchKernelGGL(mln_kernel, gMln, b64, 0, stream,
                     x_a, nullptr, valid_a, ln_a_g, ln_a_b, (float*)nullptr, lnAb);
  hipLaunchKernelGGL(mln_kernel, gMln, b64, 0, stream,
                     x_b, nullptr, valid_b, ln_b_g, ln_b_b, (float*)nullptr, lnBb);

  // fused QKV per source
  hipLaunchKernelGGL(gemm_mfma_kernel, gQKV, b128, 0, stream,
                     lnAb, Wqkv, bqkv, (float*)nullptr, QKVa, ROWS, 576, DD, 0);
  hipLaunchKernelGGL(gemm_mfma_kernel, gQKV, b128, 0, stream,
                     lnBb, Wqkv, bqkv, (float*)nullptr, QKVb, ROWS, 576, DD, 0);

  // side A: Q from a, K/V from b
  hipLaunchKernelGGL(attn_mfma_kernel, gAttn, b256, 0, stream,
                     QKVa, QKVb, valid_a, valid_b, attO);
  hipLaunchKernelGGL(gemm_mfma_kernel, gD, b128, 0, stream,
                     attO, Wo_t, bo, tmp, (ushort_t*)nullptr, ROWS, DD, DD, 0);
  hipLaunchKernelGGL(mln_kernel, gMln, b64, 0, stream,
                     tmp, x_a, valid_a, ln_oa_g, ln_oa_b, out_a, (ushort_t*)nullptr);

  // side B: Q from b, K/V from a
  hipLaunchKernelGGL(attn_mfma_kernel, gAttn, b256, 0, stream,
                     QKVb, QKVa, valid_b, valid_a, attO);
  hipLaunchKernelGGL(gemm_mfma_kernel, gD, b128, 0, stream,
                     attO, Wo_t, bo, tmp, (ushort_t*)nullptr, ROWS, DD, DD, 0);
  hipLaunchKernelGGL(mln_kernel, gMln, b64, 0, stream,
                     tmp, x_b, valid_b, ln_ob_g, ln_ob_b, out_b, (ushort_t*)nullptr);

  // FFN side A (QKV buffers now free -> Hbf)
  hipLaunchKernelGGL(mln_kernel, gMln, b64, 0, stream,
                     out_a, nullptr, valid_a, fln_g, fln_b, (float*)nullptr, lnAb);
  hipLaunchKernelGGL(gemm_mfma_kernel, gH, b128, 0, stream,
                     lnAb, W1_t, b1, (float*)nullptr, Hbf, ROWS, HID, DD, 1);
  hipLaunchKernelGGL(gemm_mfma_kernel, gD, b128, 0, stream,
                     Hbf, W2_t, b2, tmp, (ushort_t*)nullptr, ROWS, DD, HID, 0);
  hipLaunchKernelGGL(mln_kernel, gMln, b64, 0, stream,
                     out_a, tmp, valid_a, flno_g, flno_b, out_a, (ushort_t*)nullptr);

  // FFN side B
  hipLaunchKernelGGL(mln_kernel, gMln, b64, 0, stream,
                     out_b, nullptr, valid_b, fln_g, fln_b, (float*)nullptr, lnAb);
  hipLaunchKernelGGL(gemm_mfma_kernel, gH, b128, 0, stream,
                     lnAb, W1_t, b1, (float*)nullptr, Hbf, ROWS, HID, DD, 1);
  hipLaunchKernelGGL(gemm_mfma_kernel, gD, b128, 0, stream,
                     Hbf, W2_t, b2, tmp, (ushort_t*)nullptr, ROWS, DD, HID, 0);
  hipLaunchKernelGGL(mln_kernel, gMln, b64, 0, stream,
                     out_b, tmp, valid_b, flno_g, flno_b, out_b, (ushort_t*)nullptr);
}

// Round 6
// 723.760 us; speedup vs baseline: 2.3182x; 1.0850x over previous
//
#include <hip/hip_runtime.h>
#include <math.h>

#define BB 48
#define LL 512
#define DD 192
#define HH 6
#define DKK 32
#define HID 768
#define ROWS (BB * LL)
#define BLD ((size_t)ROWS * DD)
#define SCALE_ATT 0.17677669529663687f  // 1/sqrt(32)

typedef unsigned short ushort_t;
typedef unsigned int uint_t;
typedef __bf16 bf16x8 __attribute__((ext_vector_type(8)));
typedef float f32x4 __attribute__((ext_vector_type(4)));

union U4BF8 { uint4 u; bf16x8 b; };   // bit-cast helper

__device__ __forceinline__ ushort_t f2bf(float f) {
  union { float f; uint_t u; } v; v.f = f;
  uint_t r = v.u + 0x7fffu + ((v.u >> 16) & 1u);   // round-to-nearest-even
  return (ushort_t)(r >> 16);
}
__device__ __forceinline__ float bf2f(ushort_t u) {
  union { uint_t u; float f; } v; v.u = ((uint_t)u) << 16; return v.f;
}

// ---------------------------------------------------------------------------
// Pack weights: transpose to [N][K] bf16, concat QKV; concat QKV bias fp32.
// ---------------------------------------------------------------------------
__global__ __launch_bounds__(256) void pack_kernel(
    const float* __restrict__ wq, const float* __restrict__ wk,
    const float* __restrict__ wv, const float* __restrict__ wo,
    const float* __restrict__ w1, const float* __restrict__ w2,
    const float* __restrict__ bq, const float* __restrict__ bk,
    const float* __restrict__ bv,
    ushort_t* __restrict__ Wqkv, ushort_t* __restrict__ Wo,
    ushort_t* __restrict__ W1, ushort_t* __restrict__ W2,
    float* __restrict__ bqkv) {
  int i = blockIdx.x * 256 + threadIdx.x;
  if (i < 110592) {                       // Wqkv_t [576][192]
    int n2 = i / 192, k = i - n2 * 192;
    int part = n2 / 192, n = n2 - part * 192;
    const float* src = part == 0 ? wq : (part == 1 ? wk : wv);
    Wqkv[i] = f2bf(src[k * 192 + n]);
  } else if (i < 147456) {                // Wo_t [192][192]
    int j = i - 110592;
    int n = j / 192, k = j - n * 192;
    Wo[j] = f2bf(wo[k * 192 + n]);
  } else if (i < 294912) {                // W1_t [768][192]
    int j = i - 147456;
    int n = j / 192, k = j - n * 192;
    W1[j] = f2bf(w1[k * 768 + n]);
  } else if (i < 442368) {                // W2_t [192][768]
    int j = i - 294912;
    int n = j / 768, k = j - n * 768;
    W2[j] = f2bf(w2[k * 192 + n]);
  } else if (i < 442944) {                // bqkv [576]
    int j = i - 442368;
    bqkv[j] = j < 192 ? bq[j] : (j < 384 ? bk[j - 192] : bv[j - 384]);
  }
}

// ---------------------------------------------------------------------------
// Dual-side masked LayerNorm over 2*ROWS rows: side = row >= ROWS selects
// per-side x/res/valid/gamma/beta. Output contiguous at row*DD.
// ---------------------------------------------------------------------------
__global__ __launch_bounds__(64) void mln2_kernel(
    const float* __restrict__ x0, const float* __restrict__ x1,
    const float* __restrict__ res0, const float* __restrict__ res1,
    const int* __restrict__ v0, const int* __restrict__ v1,
    const float* __restrict__ g0, const float* __restrict__ be0,
    const float* __restrict__ g1, const float* __restrict__ be1,
    float* __restrict__ outf, ushort_t* __restrict__ outb) {
  int row = blockIdx.x;
  int side = row >= ROWS;
  int r = side ? row - ROWS : row;
  int lane = threadIdx.x;
  const float* x = (side ? x1 : x0) + (size_t)r * DD;
  const float* rp = side ? res1 : res0;
  const float* g = side ? g1 : g0;
  const float* be = side ? be1 : be0;
  float v0_ = x[lane], v1_ = x[lane + 64], v2_ = x[lane + 128];
  if (rp != nullptr) {
    const float* rr = rp + (size_t)r * DD;
    v0_ += rr[lane]; v1_ += rr[lane + 64]; v2_ += rr[lane + 128];
  }
  float s = v0_ + v1_ + v2_;
#pragma unroll
  for (int off = 32; off; off >>= 1) s += __shfl_xor(s, off);
  float mu = s * (1.0f / 192.0f);
  float d0 = v0_ - mu, d1 = v1_ - mu, d2 = v2_ - mu;
  float ss = d0 * d0 + d1 * d1 + d2 * d2;
#pragma unroll
  for (int off = 32; off; off >>= 1) ss += __shfl_xor(ss, off);
  float inv = rsqrtf(ss * (1.0f / 192.0f) + 1e-5f);
  float r0, r1, r2;
  if ((side ? v1 : v0)[r]) {
    r0 = d0 * inv * g[lane]       + be[lane];
    r1 = d1 * inv * g[lane + 64]  + be[lane + 64];
    r2 = d2 * inv * g[lane + 128] + be[lane + 128];
  } else {
    r0 = v0_; r1 = v1_; r2 = v2_;
  }
  size_t o = (size_t)row * DD;
  if (outf != nullptr) {
    outf[o + lane] = r0; outf[o + lane + 64] = r1; outf[o + lane + 128] = r2;
  }
  if (outb != nullptr) {
    outb[o + lane] = f2bf(r0); outb[o + lane + 64] = f2bf(r1);
    outb[o + lane + 128] = f2bf(r2);
  }
}

// ---------------------------------------------------------------------------
// bf16 MFMA GEMM (validated in R3): C = A @ Wt^T + bias
// ---------------------------------------------------------------------------
__global__ __launch_bounds__(128) void gemm_mfma_kernel(
    const ushort_t* __restrict__ A, const ushort_t* __restrict__ Wt,
    const float* __restrict__ bias, float* __restrict__ Cf,
    ushort_t* __restrict__ Cb, int M, int N, int K, int gelu) {
  __shared__ ushort_t As[128 * 40];
  __shared__ ushort_t Bs[64 * 40];
  int tid = threadIdx.x;
  int lane = tid & 63;
  int w = tid >> 6;
  int row0 = blockIdx.y * 128;
  int col0 = blockIdx.x * 64;
  int l15 = lane & 15;
  int kq = lane >> 4;

  f32x4 acc[4][4];
#pragma unroll
  for (int i = 0; i < 4; ++i)
#pragma unroll
    for (int j = 0; j < 4; ++j) acc[i][j] = (f32x4){0.f, 0.f, 0.f, 0.f};

  for (int k0 = 0; k0 < K; k0 += 32) {
    uint4 av[4], bv[2];
#pragma unroll
    for (int i = 0; i < 4; ++i) {
      int idx = tid + i * 128;
      int r = idx >> 2, qd = idx & 3;
      av[i] = *(const uint4*)(A + (size_t)(row0 + r) * K + k0 + qd * 8);
    }
#pragma unroll
    for (int i = 0; i < 2; ++i) {
      int idx = tid + i * 128;
      int n = idx >> 2, qd = idx & 3;
      bv[i] = *(const uint4*)(Wt + (size_t)(col0 + n) * K + k0 + qd * 8);
    }
    __syncthreads();
#pragma unroll
    for (int i = 0; i < 4; ++i) {
      int idx = tid + i * 128;
      int r = idx >> 2, qd = idx & 3;
      *(uint4*)(&As[r * 40 + qd * 8]) = av[i];
    }
#pragma unroll
    for (int i = 0; i < 2; ++i) {
      int idx = tid + i * 128;
      int n = idx >> 2, qd = idx & 3;
      *(uint4*)(&Bs[n * 40 + qd * 8]) = bv[i];
    }
    __syncthreads();

    bf16x8 af[4], bf[4];
#pragma unroll
    for (int mt = 0; mt < 4; ++mt)
      af[mt] = *(const bf16x8*)(&As[(w * 64 + mt * 16 + l15) * 40 + kq * 8]);
#pragma unroll
    for (int nt = 0; nt < 4; ++nt)
      bf[nt] = *(const bf16x8*)(&Bs[(nt * 16 + l15) * 40 + kq * 8]);
#pragma unroll
    for (int mt = 0; mt < 4; ++mt)
#pragma unroll
      for (int nt = 0; nt < 4; ++nt)
        acc[mt][nt] = __builtin_amdgcn_mfma_f32_16x16x32_bf16(
            af[mt], bf[nt], acc[mt][nt], 0, 0, 0);
  }

  float bcol[4];
#pragma unroll
  for (int nt = 0; nt < 4; ++nt) bcol[nt] = bias[col0 + nt * 16 + l15];
#pragma unroll
  for (int mt = 0; mt < 4; ++mt) {
#pragma unroll
    for (int nt = 0; nt < 4; ++nt) {
      int col = col0 + nt * 16 + l15;
#pragma unroll
      for (int r = 0; r < 4; ++r) {
        int row = row0 + w * 64 + mt * 16 + kq * 4 + r;
        float x = acc[mt][nt][r] + bcol[nt];
        if (gelu) x = 0.5f * x * (1.0f + erff(x * 0.70710678118654752f));
        if (Cf != nullptr) Cf[(size_t)row * N + col] = x;
        else Cb[(size_t)row * N + col] = f2bf(x);
      }
    }
  }
}

// ---------------------------------------------------------------------------
// MFMA flash attention, BOTH sides in one launch. Block 2304 = 2 sides x
// (b, h, qtile). side 0: Q rows = a (QKV rows 0..R), KV rows = b (R..2R);
// side 1 swapped. Structure identical to R5 (validated).
// ---------------------------------------------------------------------------
__global__ __launch_bounds__(256) void attn_mfma_kernel(
    const ushort_t* __restrict__ QKV,
    const int* __restrict__ valid_a, const int* __restrict__ valid_b,
    ushort_t* __restrict__ out) {
  int wg = blockIdx.x;
  const int NB = BB * HH * 4;
  int side = wg >= NB;
  int wrem = side ? wg - NB : wg;
  int qt = wrem & 3;
  int h = (wrem >> 2) % HH;
  int batch = wrem / (4 * HH);
  int tid = threadIdx.x;
  int w = tid >> 6;
  int lane = tid & 63;
  int l15 = lane & 15;
  int kq = lane >> 4;

  const int* validq = side ? valid_b : valid_a;
  const int* validk = side ? valid_a : valid_b;
  size_t qrow0  = (size_t)side * ROWS + (size_t)batch * LL;        // + q
  size_t kvrow0 = (size_t)(1 - side) * ROWS + (size_t)batch * LL;  // + k

  __shared__ ushort_t VsT[32 * 72];        // [dim][key], stride 72
  __shared__ ushort_t Ps[4][32 * 72];      // per-wave P [q][key], stride 72

  int qbase = qt * 128 + w * 32;

  U4BF8 qfrag[2];
#pragma unroll
  for (int qs = 0; qs < 2; ++qs)
    qfrag[qs].u = *(const uint4*)(QKV + (qrow0 + qbase + qs * 16 + l15) * 576 +
                                  h * DKK + kq * 8);

  int vq[2][4];
#pragma unroll
  for (int qs = 0; qs < 2; ++qs)
#pragma unroll
    for (int r = 0; r < 4; ++r)
      vq[qs][r] = validq[batch * LL + qbase + qs * 16 + kq * 4 + r];

  float mrow[2][4], lrow[2][4];
  f32x4 Oacc[2][2];
#pragma unroll
  for (int qs = 0; qs < 2; ++qs) {
#pragma unroll
    for (int r = 0; r < 4; ++r) { mrow[qs][r] = -1e30f; lrow[qs][r] = 0.0f; }
#pragma unroll
    for (int ds = 0; ds < 2; ++ds) Oacc[qs][ds] = (f32x4){0.f, 0.f, 0.f, 0.f};
  }

  for (int c = 0; c < LL; c += 64) {
    __syncthreads();   // previous chunk's VsT reads done
    uint4 vv = *(const uint4*)(QKV + (kvrow0 + c + lane) * 576 +
                               384 + h * DKK + w * 8);
    uint_t uu[4] = {vv.x, vv.y, vv.z, vv.w};
#pragma unroll
    for (int j = 0; j < 4; ++j) {
      VsT[(w * 8 + 2 * j) * 72 + lane]     = (ushort_t)(uu[j] & 0xffffu);
      VsT[(w * 8 + 2 * j + 1) * 72 + lane] = (ushort_t)(uu[j] >> 16);
    }
    __syncthreads();   // VsT ready

    f32x4 S[2][4];
    int vk[4];
#pragma unroll
    for (int ks = 0; ks < 4; ++ks) {
      U4BF8 kf;
      kf.u = *(const uint4*)(QKV + (kvrow0 + c + ks * 16 + l15) * 576 +
                             192 + h * DKK + kq * 8);
      vk[ks] = validk[batch * LL + c + ks * 16 + l15];
#pragma unroll
      for (int qs = 0; qs < 2; ++qs) {
        f32x4 z = (f32x4){0.f, 0.f, 0.f, 0.f};
        S[qs][ks] = __builtin_amdgcn_mfma_f32_16x16x32_bf16(
            qfrag[qs].b, kf.b, z, 0, 0, 0);
      }
    }

    float cm[2][4];
#pragma unroll
    for (int qs = 0; qs < 2; ++qs)
#pragma unroll
      for (int r = 0; r < 4; ++r) {
        float mx = -1e30f;
#pragma unroll
        for (int ks = 0; ks < 4; ++ks) {
          float x = (vq[qs][r] && vk[ks]) ? S[qs][ks][r] * SCALE_ATT : -1e9f;
          S[qs][ks][r] = x;
          mx = fmaxf(mx, x);
        }
        cm[qs][r] = mx;
      }
#pragma unroll
    for (int qs = 0; qs < 2; ++qs)
#pragma unroll
      for (int r = 0; r < 4; ++r) {
        float mx = cm[qs][r];
#pragma unroll
        for (int off = 1; off < 16; off <<= 1) mx = fmaxf(mx, __shfl_xor(mx, off));
        float mn = fmaxf(mrow[qs][r], mx);
        float al = __expf(mrow[qs][r] - mn);
        mrow[qs][r] = mn;
        lrow[qs][r] *= al;
#pragma unroll
        for (int ds = 0; ds < 2; ++ds) Oacc[qs][ds][r] *= al;
      }

#pragma unroll
    for (int qs = 0; qs < 2; ++qs) {
      float psum[4] = {0.f, 0.f, 0.f, 0.f};
#pragma unroll
      for (int ks = 0; ks < 4; ++ks)
#pragma unroll
        for (int r = 0; r < 4; ++r) {
          float p = __expf(S[qs][ks][r] - mrow[qs][r]);
          ushort_t pb = f2bf(p);
          psum[r] += bf2f(pb);
          Ps[w][(qs * 16 + kq * 4 + r) * 72 + ks * 16 + l15] = pb;
        }
#pragma unroll
      for (int r = 0; r < 4; ++r) {
        float sm = psum[r];
#pragma unroll
        for (int off = 1; off < 16; off <<= 1) sm += __shfl_xor(sm, off);
        lrow[qs][r] += sm;
      }
    }

#pragma unroll
    for (int kh = 0; kh < 2; ++kh) {
      bf16x8 pf[2], vf[2];
#pragma unroll
      for (int qs = 0; qs < 2; ++qs)
        pf[qs] = *(const bf16x8*)(&Ps[w][(qs * 16 + l15) * 72 + kh * 32 + kq * 8]);
#pragma unroll
      for (int ds = 0; ds < 2; ++ds)
        vf[ds] = *(const bf16x8*)(&VsT[(ds * 16 + l15) * 72 + kh * 32 + kq * 8]);
#pragma unroll
      for (int qs = 0; qs < 2; ++qs)
#pragma unroll
        for (int ds = 0; ds < 2; ++ds)
          Oacc[qs][ds] = __builtin_amdgcn_mfma_f32_16x16x32_bf16(
              pf[qs], vf[ds], Oacc[qs][ds], 0, 0, 0);
    }
  }

#pragma unroll
  for (int qs = 0; qs < 2; ++qs)
#pragma unroll
    for (int ds = 0; ds < 2; ++ds)
#pragma unroll
      for (int r = 0; r < 4; ++r) {
        int q = qbase + qs * 16 + kq * 4 + r;
        out[(qrow0 + q) * DD + h * DKK + ds * 16 + l15] =
            f2bf(Oacc[qs][ds][r] / lrow[qs][r]);
      }
}

// ---------------------------------------------------------------------------
extern "C" void kernel_launch(void* const* d_in, const int* in_sizes, int n_in,
                              void* d_out, int out_size, void* d_ws, size_t ws_size,
                              hipStream_t stream) {
  const float* x_a = (const float*)d_in[0];
  const float* x_b = (const float*)d_in[1];
  const int* valid_a = (const int*)d_in[2];
  const int* valid_b = (const int*)d_in[3];
  const float* ln_a_g = (const float*)d_in[4];
  const float* ln_a_b = (const float*)d_in[5];
  const float* ln_b_g = (const float*)d_in[6];
  const float* ln_b_b = (const float*)d_in[7];
  const float* ln_oa_g = (const float*)d_in[8];
  const float* ln_oa_b = (const float*)d_in[9];
  const float* ln_ob_g = (const float*)d_in[10];
  const float* ln_ob_b = (const float*)d_in[11];
  const float* wq = (const float*)d_in[12];
  const float* bq = (const float*)d_in[13];
  const float* wk = (const float*)d_in[14];
  const float* bk = (const float*)d_in[15];
  const float* wv = (const float*)d_in[16];
  const float* bv = (const float*)d_in[17];
  const float* wo = (const float*)d_in[18];
  const float* bo = (const float*)d_in[19];
  const float* fln_g = (const float*)d_in[20];
  const float* fln_b = (const float*)d_in[21];
  const float* flno_g = (const float*)d_in[22];
  const float* flno_b = (const float*)d_in[23];
  const float* w1 = (const float*)d_in[24];
  const float* b1 = (const float*)d_in[25];
  const float* w2 = (const float*)d_in[26];
  const float* b2 = (const float*)d_in[27];

  // Workspace layout (bytes):
  //  [0,          56623104)  QKV  [2R,576] bf16   / Hbf [R,768] bf16 (overlay)
  //  [56623104,   75497472)  lnFull/attO [2R,192] bf16 (union; disjoint lifetimes)
  //  [75497472,  113246208)  tmp  [2R,192] fp32
  //  [113246208, 114133248)  packed weights + bqkv
  char* wsb = (char*)d_ws;
  ushort_t* QKV    = (ushort_t*)wsb;
  ushort_t* Hbf    = (ushort_t*)wsb;
  ushort_t* lnFull = (ushort_t*)(wsb + 56623104);
  ushort_t* attO   = (ushort_t*)(wsb + 56623104);
  float*    tmp    = (float*)(wsb + 75497472);
  ushort_t* Wqkv   = (ushort_t*)(wsb + 113246208);
  ushort_t* Wo_t   = Wqkv + 110592;
  ushort_t* W1_t   = Wo_t + 36864;
  ushort_t* W2_t   = W1_t + 147456;
  float*    bqkv   = (float*)(W2_t + 147456);

  float* out_a = (float*)d_out;                 // [2R,192] fp32 contiguous

  dim3 b64(64), b128(128), b256(256);
  dim3 gMln(2 * ROWS);
  dim3 gQKV(576 / 64, 2 * ROWS / 128);          // (9, 384)
  dim3 gAttn(BB * HH * 4 * 2);                  // 2304
  dim3 gO(DD / 64, 2 * ROWS / 128);             // (3, 384)
  dim3 gW1(HID / 64, ROWS / 128);               // (12, 192)
  dim3 gW2(DD / 64, ROWS / 128);                // (3, 192)

  hipLaunchKernelGGL(pack_kernel, dim3(1731), b256, 0, stream,
                     wq, wk, wv, wo, w1, w2, bq, bk, bv,
                     Wqkv, Wo_t, W1_t, W2_t, bqkv);

  // 1. pre-LN both sides -> lnFull bf16
  hipLaunchKernelGGL(mln2_kernel, gMln, b64, 0, stream,
                     x_a, x_b, (const float*)nullptr, (const float*)nullptr,
                     valid_a, valid_b, ln_a_g, ln_a_b, ln_b_g, ln_b_b,
                     (float*)nullptr, lnFull);

  // 2. fused QKV, both sides (M = 2R)
  hipLaunchKernelGGL(gemm_mfma_kernel, gQKV, b128, 0, stream,
                     lnFull, Wqkv, bqkv, (float*)nullptr, QKV,
                     2 * ROWS, 576, DD, 0);

  // 3. attention, both sides
  hipLaunchKernelGGL(attn_mfma_kernel, gAttn, b256, 0, stream,
                     QKV, valid_a, valid_b, attO);

  // 4. O-projection, both sides (M = 2R) -> tmp fp32
  hipLaunchKernelGGL(gemm_mfma_kernel, gO, b128, 0, stream,
                     attO, Wo_t, bo, tmp, (ushort_t*)nullptr,
                     2 * ROWS, DD, DD, 0);

  // 5. residual + LN -> d_out fp32
  hipLaunchKernelGGL(mln2_kernel, gMln, b64, 0, stream,
                     tmp, tmp + BLD, x_a, x_b,
                     valid_a, valid_b, ln_oa_g, ln_oa_b, ln_ob_g, ln_ob_b,
                     out_a, (ushort_t*)nullptr);

  // 6. FFN pre-LN both sides -> lnFull bf16 (attO dead)
  hipLaunchKernelGGL(mln2_kernel, gMln, b64, 0, stream,
                     out_a, out_a + BLD, (const float*)nullptr, (const float*)nullptr,
                     valid_a, valid_b, fln_g, fln_b, fln_g, fln_b,
                     (float*)nullptr, lnFull);

  // 7. FFN per side (Hbf overlays dead QKV region)
  hipLaunchKernelGGL(gemm_mfma_kernel, gW1, b128, 0, stream,
                     lnFull, W1_t, b1, (float*)nullptr, Hbf, ROWS, HID, DD, 1);
  hipLaunchKernelGGL(gemm_mfma_kernel, gW2, b128, 0, stream,
                     Hbf, W2_t, b2, tmp, (ushort_t*)nullptr, ROWS, DD, HID, 0);
  hipLaunchKernelGGL(gemm_mfma_kernel, gW1, b128, 0, stream,
                     lnFull + BLD, W1_t, b1, (float*)nullptr, Hbf, ROWS, HID, DD, 1);
  hipLaunchKernelGGL(gemm_mfma_kernel, gW2, b128, 0, stream,
                     Hbf, W2_t, b2, tmp + BLD, (ushort_t*)nullptr, ROWS, DD, HID, 0);

  // 8. FFN residual + LN -> d_out
  hipLaunchKernelGGL(mln2_kernel, gMln, b64, 0, stream,
                     tmp, tmp + BLD, out_a, out_a + BLD,
                     valid_a, valid_b, flno_g, flno_b, flno_g, flno_b,
                     out_a, (ushort_t*)nullptr);
}

// Round 7
// 696.471 us; speedup vs baseline: 2.4091x; 1.0392x over previous
//
#include <hip/hip_runtime.h>
#include <math.h>

#define BB 48
#define LL 512
#define DD 192
#define HH 6
#define DKK 32
#define HID 768
#define ROWS (BB * LL)
#define BLD ((size_t)ROWS * DD)
#define SCALE_ATT 0.17677669529663687f  // 1/sqrt(32)
#define MASKED_S (-25.0f)               // exp(-25)=1.4e-11: negligible yet uniform for all-masked rows

typedef unsigned short ushort_t;
typedef unsigned int uint_t;
typedef __bf16 bf16x8 __attribute__((ext_vector_type(8)));
typedef float f32x4 __attribute__((ext_vector_type(4)));

union U4BF8 { uint4 u; bf16x8 b; };

__device__ __forceinline__ ushort_t f2bf(float f) {
  union { float f; uint_t u; } v; v.f = f;
  uint_t r = v.u + 0x7fffu + ((v.u >> 16) & 1u);
  return (ushort_t)(r >> 16);
}
__device__ __forceinline__ float bf2f(ushort_t u) {
  union { uint_t u; float f; } v; v.u = ((uint_t)u) << 16; return v.f;
}

// ---------------------------------------------------------------------------
__global__ __launch_bounds__(256) void pack_kernel(
    const float* __restrict__ wq, const float* __restrict__ wk,
    const float* __restrict__ wv, const float* __restrict__ wo,
    const float* __restrict__ w1, const float* __restrict__ w2,
    const float* __restrict__ bq, const float* __restrict__ bk,
    const float* __restrict__ bv,
    ushort_t* __restrict__ Wqkv, ushort_t* __restrict__ Wo,
    ushort_t* __restrict__ W1, ushort_t* __restrict__ W2,
    float* __restrict__ bqkv) {
  int i = blockIdx.x * 256 + threadIdx.x;
  if (i < 110592) {                       // Wqkv_t [576][192]
    int n2 = i / 192, k = i - n2 * 192;
    int part = n2 / 192, n = n2 - part * 192;
    const float* src = part == 0 ? wq : (part == 1 ? wk : wv);
    Wqkv[i] = f2bf(src[k * 192 + n]);
  } else if (i < 147456) {                // Wo_t [192][192]
    int j = i - 110592;
    int n = j / 192, k = j - n * 192;
    Wo[j] = f2bf(wo[k * 192 + n]);
  } else if (i < 294912) {                // W1_t [768][192]
    int j = i - 147456;
    int n = j / 192, k = j - n * 192;
    W1[j] = f2bf(w1[k * 768 + n]);
  } else if (i < 442368) {                // W2_t [192][768]
    int j = i - 294912;
    int n = j / 768, k = j - n * 768;
    W2[j] = f2bf(w2[k * 192 + n]);
  } else if (i < 442944) {                // bqkv [576]
    int j = i - 442368;
    bqkv[j] = j < 192 ? bq[j] : (j < 384 ? bk[j - 192] : bv[j - 384]);
  }
}

// ---------------------------------------------------------------------------
// Dual-side masked LayerNorm over 2*ROWS rows (steps 1 and 8).
// ---------------------------------------------------------------------------
__global__ __launch_bounds__(64) void mln2_kernel(
    const float* __restrict__ x0, const float* __restrict__ x1,
    const float* __restrict__ res0, const float* __restrict__ res1,
    const int* __restrict__ v0, const int* __restrict__ v1,
    const float* __restrict__ g0, const float* __restrict__ be0,
    const float* __restrict__ g1, const float* __restrict__ be1,
    float* __restrict__ outf, ushort_t* __restrict__ outb) {
  int row = blockIdx.x;
  int side = row >= ROWS;
  int r = side ? row - ROWS : row;
  int lane = threadIdx.x;
  const float* x = (side ? x1 : x0) + (size_t)r * DD;
  const float* rp = side ? res1 : res0;
  const float* g = side ? g1 : g0;
  const float* be = side ? be1 : be0;
  float v0_ = x[lane], v1_ = x[lane + 64], v2_ = x[lane + 128];
  if (rp != nullptr) {
    const float* rr = rp + (size_t)r * DD;
    v0_ += rr[lane]; v1_ += rr[lane + 64]; v2_ += rr[lane + 128];
  }
  float s = v0_ + v1_ + v2_;
#pragma unroll
  for (int off = 32; off; off >>= 1) s += __shfl_xor(s, off);
  float mu = s * (1.0f / 192.0f);
  float d0 = v0_ - mu, d1 = v1_ - mu, d2 = v2_ - mu;
  float ss = d0 * d0 + d1 * d1 + d2 * d2;
#pragma unroll
  for (int off = 32; off; off >>= 1) ss += __shfl_xor(ss, off);
  float inv = rsqrtf(ss * (1.0f / 192.0f) + 1e-5f);
  float r0, r1, r2;
  if ((side ? v1 : v0)[r]) {
    r0 = d0 * inv * g[lane]       + be[lane];
    r1 = d1 * inv * g[lane + 64]  + be[lane + 64];
    r2 = d2 * inv * g[lane + 128] + be[lane + 128];
  } else {
    r0 = v0_; r1 = v1_; r2 = v2_;
  }
  size_t o = (size_t)row * DD;
  if (outf != nullptr) {
    outf[o + lane] = r0; outf[o + lane + 64] = r1; outf[o + lane + 128] = r2;
  }
  if (outb != nullptr) {
    outb[o + lane] = f2bf(r0); outb[o + lane + 64] = f2bf(r1);
    outb[o + lane + 128] = f2bf(r2);
  }
}

// ---------------------------------------------------------------------------
// Fused chain (steps 5+6): y = mln(t + res, ln_oX) -> outf (fp32, d_out);
// z = mln(y, fln) -> outb (bf16, FFN input). One memory pass.
// ---------------------------------------------------------------------------
__global__ __launch_bounds__(64) void mln_chain_kernel(
    const float* __restrict__ t,
    const float* __restrict__ res0, const float* __restrict__ res1,
    const int* __restrict__ v0, const int* __restrict__ v1,
    const float* __restrict__ g1a, const float* __restrict__ b1a,
    const float* __restrict__ g1b, const float* __restrict__ b1b,
    const float* __restrict__ g2, const float* __restrict__ b2,
    float* __restrict__ outf, ushort_t* __restrict__ outb) {
  int row = blockIdx.x;
  int side = row >= ROWS;
  int r = side ? row - ROWS : row;
  int lane = threadIdx.x;
  const float* tr = t + (size_t)row * DD;
  const float* rr = (side ? res1 : res0) + (size_t)r * DD;
  const float* g1 = side ? g1b : g1a;
  const float* b1 = side ? b1b : b1a;
  int vld = (side ? v1 : v0)[r];
  float v0_ = tr[lane] + rr[lane];
  float v1_ = tr[lane + 64] + rr[lane + 64];
  float v2_ = tr[lane + 128] + rr[lane + 128];
  // LN1
  float s = v0_ + v1_ + v2_;
#pragma unroll
  for (int off = 32; off; off >>= 1) s += __shfl_xor(s, off);
  float mu = s * (1.0f / 192.0f);
  float d0 = v0_ - mu, d1 = v1_ - mu, d2 = v2_ - mu;
  float ss = d0 * d0 + d1 * d1 + d2 * d2;
#pragma unroll
  for (int off = 32; off; off >>= 1) ss += __shfl_xor(ss, off);
  float inv = rsqrtf(ss * (1.0f / 192.0f) + 1e-5f);
  float y0, y1, y2;
  if (vld) {
    y0 = d0 * inv * g1[lane]       + b1[lane];
    y1 = d1 * inv * g1[lane + 64]  + b1[lane + 64];
    y2 = d2 * inv * g1[lane + 128] + b1[lane + 128];
  } else { y0 = v0_; y1 = v1_; y2 = v2_; }
  size_t o = (size_t)row * DD;
  outf[o + lane] = y0; outf[o + lane + 64] = y1; outf[o + lane + 128] = y2;
  // LN2
  float s2 = y0 + y1 + y2;
#pragma unroll
  for (int off = 32; off; off >>= 1) s2 += __shfl_xor(s2, off);
  float mu2 = s2 * (1.0f / 192.0f);
  float e0 = y0 - mu2, e1 = y1 - mu2, e2 = y2 - mu2;
  float ss2 = e0 * e0 + e1 * e1 + e2 * e2;
#pragma unroll
  for (int off = 32; off; off >>= 1) ss2 += __shfl_xor(ss2, off);
  float inv2 = rsqrtf(ss2 * (1.0f / 192.0f) + 1e-5f);
  float z0, z1, z2;
  if (vld) {
    z0 = e0 * inv2 * g2[lane]       + b2[lane];
    z1 = e1 * inv2 * g2[lane + 64]  + b2[lane + 64];
    z2 = e2 * inv2 * g2[lane + 128] + b2[lane + 128];
  } else { z0 = y0; z1 = y1; z2 = y2; }
  outb[o + lane] = f2bf(z0); outb[o + lane + 64] = f2bf(z1);
  outb[o + lane + 128] = f2bf(z2);
}

// ---------------------------------------------------------------------------
// bf16 MFMA GEMM with ping-pong register prefetch. C = A @ Wt^T + bias.
// 128x64 tile, 128 threads; K multiple of 64 (iters even).
// ---------------------------------------------------------------------------
__global__ __launch_bounds__(128) void gemm_mfma_kernel(
    const ushort_t* __restrict__ A, const ushort_t* __restrict__ Wt,
    const float* __restrict__ bias, float* __restrict__ Cf,
    ushort_t* __restrict__ Cb, int M, int N, int K, int gelu) {
  __shared__ ushort_t As[128 * 40];
  __shared__ ushort_t Bs[64 * 40];
  int tid = threadIdx.x;
  int lane = tid & 63;
  int w = tid >> 6;
  int row0 = blockIdx.y * 128;
  int col0 = blockIdx.x * 64;
  int l15 = lane & 15;
  int kq = lane >> 4;

  int lr = tid >> 2, lq = tid & 3;        // A load: row, k-quad
  int lr2 = (tid + 128) >> 2, lq2 = (tid + 128) & 3;
  int nr = tid >> 2, nq = tid & 3;        // B load (same pattern, 2 chunks)

  f32x4 acc[4][4];
#pragma unroll
  for (int i = 0; i < 4; ++i)
#pragma unroll
    for (int j = 0; j < 4; ++j) acc[i][j] = (f32x4){0.f, 0.f, 0.f, 0.f};

#define LOADAB(AV, BV, K0)                                                   \
  {                                                                          \
    AV[0] = *(const uint4*)(A + (size_t)(row0 + lr) * K + (K0) + lq * 8);    \
    AV[1] = *(const uint4*)(A + (size_t)(row0 + lr2) * K + (K0) + lq2 * 8);  \
    AV[2] = *(const uint4*)(A + (size_t)(row0 + lr + 64) * K + (K0) + lq * 8);   \
    AV[3] = *(const uint4*)(A + (size_t)(row0 + lr2 + 64) * K + (K0) + lq2 * 8); \
    BV[0] = *(const uint4*)(Wt + (size_t)(col0 + nr) * K + (K0) + nq * 8);   \
    BV[1] = *(const uint4*)(Wt + (size_t)(col0 + nr + 32) * K + (K0) + nq * 8);  \
  }

#define STOREAB(AV, BV)                                                      \
  {                                                                          \
    *(uint4*)(&As[lr * 40 + lq * 8]) = AV[0];                                \
    *(uint4*)(&As[lr2 * 40 + lq2 * 8]) = AV[1];                              \
    *(uint4*)(&As[(lr + 64) * 40 + lq * 8]) = AV[2];                         \
    *(uint4*)(&As[(lr2 + 64) * 40 + lq2 * 8]) = AV[3];                       \
    *(uint4*)(&Bs[nr * 40 + nq * 8]) = BV[0];                                \
    *(uint4*)(&Bs[(nr + 32) * 40 + nq * 8]) = BV[1];                         \
  }

#define COMPUTE()                                                            \
  {                                                                          \
    bf16x8 af[4], bf[4];                                                     \
    _Pragma("unroll") for (int mt = 0; mt < 4; ++mt)                         \
      af[mt] = *(const bf16x8*)(&As[(w * 64 + mt * 16 + l15) * 40 + kq * 8]);\
    _Pragma("unroll") for (int nt = 0; nt < 4; ++nt)                         \
      bf[nt] = *(const bf16x8*)(&Bs[(nt * 16 + l15) * 40 + kq * 8]);         \
    _Pragma("unroll") for (int mt = 0; mt < 4; ++mt)                         \
      _Pragma("unroll") for (int nt = 0; nt < 4; ++nt)                       \
        acc[mt][nt] = __builtin_amdgcn_mfma_f32_16x16x32_bf16(               \
            af[mt], bf[nt], acc[mt][nt], 0, 0, 0);                           \
  }

  int iters = K >> 5;   // always even here (K = 192 or 768)
  uint4 avA[4], bvA[2], avB[4], bvB[2];
  LOADAB(avA, bvA, 0)
  for (int it = 0; it < iters; it += 2) {
    __syncthreads();
    STOREAB(avA, bvA)
    __syncthreads();
    if (it + 1 < iters) LOADAB(avB, bvB, (it + 1) << 5)
    COMPUTE()
    __syncthreads();
    STOREAB(avB, bvB)
    __syncthreads();
    if (it + 2 < iters) LOADAB(avA, bvA, (it + 2) << 5)
    COMPUTE()
  }
#undef LOADAB
#undef STOREAB
#undef COMPUTE

  float bcol[4];
#pragma unroll
  for (int nt = 0; nt < 4; ++nt) bcol[nt] = bias[col0 + nt * 16 + l15];
#pragma unroll
  for (int mt = 0; mt < 4; ++mt) {
#pragma unroll
    for (int nt = 0; nt < 4; ++nt) {
      int col = col0 + nt * 16 + l15;
#pragma unroll
      for (int r = 0; r < 4; ++r) {
        int row = row0 + w * 64 + mt * 16 + kq * 4 + r;
        float x = acc[mt][nt][r] + bcol[nt];
        if (gelu) x = 0.5f * x * (1.0f + erff(x * 0.70710678118654752f));
        if (Cf != nullptr) Cf[(size_t)row * N + col] = x;
        else Cb[(size_t)row * N + col] = f2bf(x);
      }
    }
  }
}

// ---------------------------------------------------------------------------
// MFMA flash attention, both sides, NO online max (scores bounded; masked
// pairs use -25 so fully-masked rows give exactly uniform softmax).
// XCD swizzle: i&7 = XCD slot; the 4 q-tiles of one (b,h,side) share it.
// ---------------------------------------------------------------------------
__global__ __launch_bounds__(256) void attn_mfma_kernel(
    const ushort_t* __restrict__ QKV,
    const int* __restrict__ valid_a, const int* __restrict__ valid_b,
    ushort_t* __restrict__ out) {
  int i = blockIdx.x;
  int gid = ((i >> 5) << 3) | (i & 7);    // 0..575: (side,batch,h)
  int qt = (i >> 3) & 3;
  int side = gid >= BB * HH;
  int grem = side ? gid - BB * HH : gid;
  int h = grem % HH;
  int batch = grem / HH;
  int tid = threadIdx.x;
  int w = tid >> 6;
  int lane = tid & 63;
  int l15 = lane & 15;
  int kq = lane >> 4;

  const int* validq = side ? valid_b : valid_a;
  const int* validk = side ? valid_a : valid_b;
  size_t qrow0  = (size_t)side * ROWS + (size_t)batch * LL;
  size_t kvrow0 = (size_t)(1 - side) * ROWS + (size_t)batch * LL;

  __shared__ ushort_t VsT[32 * 72];
  __shared__ ushort_t Ps[4][32 * 72];

  int qbase = qt * 128 + w * 32;

  U4BF8 qfrag[2];
#pragma unroll
  for (int qs = 0; qs < 2; ++qs)
    qfrag[qs].u = *(const uint4*)(QKV + (qrow0 + qbase + qs * 16 + l15) * 576 +
                                  h * DKK + kq * 8);

  int vq[2][4];
#pragma unroll
  for (int qs = 0; qs < 2; ++qs)
#pragma unroll
    for (int r = 0; r < 4; ++r)
      vq[qs][r] = validq[batch * LL + qbase + qs * 16 + kq * 4 + r];

  float lsum[2][4];
  f32x4 Oacc[2][2];
#pragma unroll
  for (int qs = 0; qs < 2; ++qs) {
#pragma unroll
    for (int r = 0; r < 4; ++r) lsum[qs][r] = 0.0f;
#pragma unroll
    for (int ds = 0; ds < 2; ++ds) Oacc[qs][ds] = (f32x4){0.f, 0.f, 0.f, 0.f};
  }

  for (int c = 0; c < LL; c += 64) {
    __syncthreads();
    uint4 vv = *(const uint4*)(QKV + (kvrow0 + c + lane) * 576 +
                               384 + h * DKK + w * 8);
    uint_t uu[4] = {vv.x, vv.y, vv.z, vv.w};
#pragma unroll
    for (int j = 0; j < 4; ++j) {
      VsT[(w * 8 + 2 * j) * 72 + lane]     = (ushort_t)(uu[j] & 0xffffu);
      VsT[(w * 8 + 2 * j + 1) * 72 + lane] = (ushort_t)(uu[j] >> 16);
    }
    __syncthreads();

    f32x4 S[2][4];
    int vk[4];
#pragma unroll
    for (int ks = 0; ks < 4; ++ks) {
      U4BF8 kf;
      kf.u = *(const uint4*)(QKV + (kvrow0 + c + ks * 16 + l15) * 576 +
                             192 + h * DKK + kq * 8);
      vk[ks] = validk[batch * LL + c + ks * 16 + l15];
#pragma unroll
      for (int qs = 0; qs < 2; ++qs) {
        f32x4 z = (f32x4){0.f, 0.f, 0.f, 0.f};
        S[qs][ks] = __builtin_amdgcn_mfma_f32_16x16x32_bf16(
            qfrag[qs].b, kf.b, z, 0, 0, 0);
      }
    }

    // P = exp(mask ? s*scale : -25); no max subtraction (|s*scale| <~ 1)
#pragma unroll
    for (int qs = 0; qs < 2; ++qs)
#pragma unroll
      for (int ks = 0; ks < 4; ++ks)
#pragma unroll
        for (int r = 0; r < 4; ++r) {
          float x = (vq[qs][r] && vk[ks]) ? S[qs][ks][r] * SCALE_ATT : MASKED_S;
          float p = __expf(x);
          ushort_t pb = f2bf(p);
          lsum[qs][r] += bf2f(pb);
          Ps[w][(qs * 16 + kq * 4 + r) * 72 + ks * 16 + l15] = pb;
        }

#pragma unroll
    for (int kh = 0; kh < 2; ++kh) {
      bf16x8 pf[2], vf[2];
#pragma unroll
      for (int qs = 0; qs < 2; ++qs)
        pf[qs] = *(const bf16x8*)(&Ps[w][(qs * 16 + l15) * 72 + kh * 32 + kq * 8]);
#pragma unroll
      for (int ds = 0; ds < 2; ++ds)
        vf[ds] = *(const bf16x8*)(&VsT[(ds * 16 + l15) * 72 + kh * 32 + kq * 8]);
#pragma unroll
      for (int qs = 0; qs < 2; ++qs)
#pragma unroll
        for (int ds = 0; ds < 2; ++ds)
          Oacc[qs][ds] = __builtin_amdgcn_mfma_f32_16x16x32_bf16(
              pf[qs], vf[ds], Oacc[qs][ds], 0, 0, 0);
    }
  }

  // single final l reduction across the 16 lanes sharing each row
#pragma unroll
  for (int qs = 0; qs < 2; ++qs)
#pragma unroll
    for (int r = 0; r < 4; ++r) {
      float sm = lsum[qs][r];
#pragma unroll
      for (int off = 1; off < 16; off <<= 1) sm += __shfl_xor(sm, off);
      lsum[qs][r] = sm;
    }

#pragma unroll
  for (int qs = 0; qs < 2; ++qs)
#pragma unroll
    for (int ds = 0; ds < 2; ++ds)
#pragma unroll
      for (int r = 0; r < 4; ++r) {
        int q = qbase + qs * 16 + kq * 4 + r;
        out[(qrow0 + q) * DD + h * DKK + ds * 16 + l15] =
            f2bf(Oacc[qs][ds][r] / lsum[qs][r]);
      }
}

// ---------------------------------------------------------------------------
extern "C" void kernel_launch(void* const* d_in, const int* in_sizes, int n_in,
                              void* d_out, int out_size, void* d_ws, size_t ws_size,
                              hipStream_t stream) {
  const float* x_a = (const float*)d_in[0];
  const float* x_b = (const float*)d_in[1];
  const int* valid_a = (const int*)d_in[2];
  const int* valid_b = (const int*)d_in[3];
  const float* ln_a_g = (const float*)d_in[4];
  const float* ln_a_b = (const float*)d_in[5];
  const float* ln_b_g = (const float*)d_in[6];
  const float* ln_b_b = (const float*)d_in[7];
  const float* ln_oa_g = (const float*)d_in[8];
  const float* ln_oa_b = (const float*)d_in[9];
  const float* ln_ob_g = (const float*)d_in[10];
  const float* ln_ob_b = (const float*)d_in[11];
  const float* wq = (const float*)d_in[12];
  const float* bq = (const float*)d_in[13];
  const float* wk = (const float*)d_in[14];
  const float* bk = (const float*)d_in[15];
  const float* wv = (const float*)d_in[16];
  const float* bv = (const float*)d_in[17];
  const float* wo = (const float*)d_in[18];
  const float* bo = (const float*)d_in[19];
  const float* fln_g = (const float*)d_in[20];
  const float* fln_b = (const float*)d_in[21];
  const float* flno_g = (const float*)d_in[22];
  const float* flno_b = (const float*)d_in[23];
  const float* w1 = (const float*)d_in[24];
  const float* b1 = (const float*)d_in[25];
  const float* w2 = (const float*)d_in[26];
  const float* b2 = (const float*)d_in[27];

  // Workspace layout (bytes):
  //   [0, 887040)                 packed weights + bqkv
  //   [887040, 19761408)          lnFull / attO [2R,192] bf16 (disjoint lifetimes)
  //   [19761408, +75497472|56623104) QKV [2R,576] bf16 / Hbf overlay
  //   tmp [2R,192] fp32 after that
  // big mode (FFN merged across sides, Hbf=2R x 768) needs 133007616 B.
  char* wsb = (char*)d_ws;
  ushort_t* Wqkv = (ushort_t*)wsb;
  ushort_t* Wo_t = Wqkv + 110592;
  ushort_t* W1_t = Wo_t + 36864;
  ushort_t* W2_t = W1_t + 147456;
  float*    bqkv = (float*)(W2_t + 147456);
  ushort_t* lnFull = (ushort_t*)(wsb + 887040);
  ushort_t* attO   = lnFull;
  ushort_t* QKV = (ushort_t*)(wsb + 19761408);
  ushort_t* Hbf = QKV;
  bool bigws = ws_size >= (size_t)133007616;
  float* tmp = (float*)(wsb + 19761408 + (bigws ? 75497472 : 56623104));

  float* out_a = (float*)d_out;   // [2R,192] fp32 contiguous

  dim3 b64(64), b128(128), b256(256);
  dim3 gMln(2 * ROWS);
  dim3 gQKV(576 / 64, 2 * ROWS / 128);          // (9, 384)
  dim3 gAttn(BB * HH * 4 * 2);                  // 2304
  dim3 gO(DD / 64, 2 * ROWS / 128);             // (3, 384)

  hipLaunchKernelGGL(pack_kernel, dim3(1731), b256, 0, stream,
                     wq, wk, wv, wo, w1, w2, bq, bk, bv,
                     Wqkv, Wo_t, W1_t, W2_t, bqkv);

  // 1. pre-LN both sides -> lnFull bf16
  hipLaunchKernelGGL(mln2_kernel, gMln, b64, 0, stream,
                     x_a, x_b, (const float*)nullptr, (const float*)nullptr,
                     valid_a, valid_b, ln_a_g, ln_a_b, ln_b_g, ln_b_b,
                     (float*)nullptr, lnFull);

  // 2. fused QKV, both sides
  hipLaunchKernelGGL(gemm_mfma_kernel, gQKV, b128, 0, stream,
                     lnFull, Wqkv, bqkv, (float*)nullptr, QKV,
                     2 * ROWS, 576, DD, 0);

  // 3. attention, both sides
  hipLaunchKernelGGL(attn_mfma_kernel, gAttn, b256, 0, stream,
                     QKV, valid_a, valid_b, attO);

  // 4. O-projection, both sides -> tmp fp32
  hipLaunchKernelGGL(gemm_mfma_kernel, gO, b128, 0, stream,
                     attO, Wo_t, bo, tmp, (ushort_t*)nullptr,
                     2 * ROWS, DD, DD, 0);

  // 5+6. fused residual-LN -> d_out fp32, then FFN pre-LN -> lnFull bf16
  hipLaunchKernelGGL(mln_chain_kernel, gMln, b64, 0, stream,
                     tmp, x_a, x_b, valid_a, valid_b,
                     ln_oa_g, ln_oa_b, ln_ob_g, ln_ob_b, fln_g, fln_b,
                     out_a, lnFull);

  // 7. FFN
  if (bigws) {
    dim3 gW1(HID / 64, 2 * ROWS / 128);         // (12, 384)
    dim3 gW2(DD / 64, 2 * ROWS / 128);          // (3, 384)
    hipLaunchKernelGGL(gemm_mfma_kernel, gW1, b128, 0, stream,
                       lnFull, W1_t, b1, (float*)nullptr, Hbf,
                       2 * ROWS, HID, DD, 1);
    hipLaunchKernelGGL(gemm_mfma_kernel, gW2, b128, 0, stream,
                       Hbf, W2_t, b2, tmp, (ushort_t*)nullptr,
                       2 * ROWS, DD, HID, 0);
  } else {
    dim3 gW1(HID / 64, ROWS / 128);
    dim3 gW2(DD / 64, ROWS / 128);
    hipLaunchKernelGGL(gemm_mfma_kernel, gW1, b128, 0, stream,
                       lnFull, W1_t, b1, (float*)nullptr, Hbf, ROWS, HID, DD, 1);
    hipLaunchKernelGGL(gemm_mfma_kernel, gW2, b128, 0, stream,
                       Hbf, W2_t, b2, tmp, (ushort_t*)nullptr, ROWS, DD, HID, 0);
    hipLaunchKernelGGL(gemm_mfma_kernel, gW1, b128, 0, stream,
                       lnFull + BLD, W1_t, b1, (float*)nullptr, Hbf, ROWS, HID, DD, 1);
    hipLaunchKernelGGL(gemm_mfma_kernel, gW2, b128, 0, stream,
                       Hbf, W2_t, b2, tmp + BLD, (ushort_t*)nullptr, ROWS, DD, HID, 0);
  }

  // 8. FFN residual + LN -> d_out
  hipLaunchKernelGGL(mln2_kernel, gMln, b64, 0, stream,
                     tmp, tmp + BLD, out_a, out_a + BLD,
                     valid_a, valid_b, flno_g, flno_b, flno_g, flno_b,
                     out_a, (ushort_t*)nullptr);
}

// Round 8
// 513.315 us; speedup vs baseline: 3.2687x; 1.3568x over previous
//
#include <hip/hip_runtime.h>
#include <math.h>

#define BB 48
#define LL 512
#define DD 192
#define HH 6
#define DKK 32
#define HID 768
#define ROWS (BB * LL)
#define BLD ((size_t)ROWS * DD)
#define SCALE_ATT 0.17677669529663687f  // 1/sqrt(32)
#define MASKED_S (-25.0f)

typedef unsigned short ushort_t;
typedef unsigned int uint_t;
typedef __bf16 bf16x8 __attribute__((ext_vector_type(8)));
typedef float f32x4 __attribute__((ext_vector_type(4)));

union U4BF8 { uint4 u; bf16x8 b; };

__device__ __forceinline__ ushort_t f2bf(float f) {
  union { float f; uint_t u; } v; v.f = f;
  uint_t r = v.u + 0x7fffu + ((v.u >> 16) & 1u);
  return (ushort_t)(r >> 16);
}
__device__ __forceinline__ float bf2f(ushort_t u) {
  union { uint_t u; float f; } v; v.u = ((uint_t)u) << 16; return v.f;
}

// ---------------------------------------------------------------------------
__global__ __launch_bounds__(256) void pack_kernel(
    const float* __restrict__ wq, const float* __restrict__ wk,
    const float* __restrict__ wv, const float* __restrict__ wo,
    const float* __restrict__ w1, const float* __restrict__ w2,
    const float* __restrict__ bq, const float* __restrict__ bk,
    const float* __restrict__ bv,
    ushort_t* __restrict__ Wqkv, ushort_t* __restrict__ Wo,
    ushort_t* __restrict__ W1, ushort_t* __restrict__ W2,
    float* __restrict__ bqkv) {
  int i = blockIdx.x * 256 + threadIdx.x;
  if (i < 110592) {                       // Wqkv_t [576][192]
    int n2 = i / 192, k = i - n2 * 192;
    int part = n2 / 192, n = n2 - part * 192;
    const float* src = part == 0 ? wq : (part == 1 ? wk : wv);
    Wqkv[i] = f2bf(src[k * 192 + n]);
  } else if (i < 147456) {                // Wo_t [192][192]
    int j = i - 110592;
    int n = j / 192, k = j - n * 192;
    Wo[j] = f2bf(wo[k * 192 + n]);
  } else if (i < 294912) {                // W1_t [768][192]
    int j = i - 147456;
    int n = j / 192, k = j - n * 192;
    W1[j] = f2bf(w1[k * 768 + n]);
  } else if (i < 442368) {                // W2_t [192][768]
    int j = i - 294912;
    int n = j / 768, k = j - n * 768;
    W2[j] = f2bf(w2[k * 192 + n]);
  } else if (i < 442944) {                // bqkv [576]
    int j = i - 442368;
    bqkv[j] = j < 192 ? bq[j] : (j < 384 ? bk[j - 192] : bv[j - 384]);
  }
}

// ---------------------------------------------------------------------------
// Dual-side masked LayerNorm over 2*ROWS rows.
// ---------------------------------------------------------------------------
__global__ __launch_bounds__(64) void mln2_kernel(
    const float* __restrict__ x0, const float* __restrict__ x1,
    const float* __restrict__ res0, const float* __restrict__ res1,
    const int* __restrict__ v0, const int* __restrict__ v1,
    const float* __restrict__ g0, const float* __restrict__ be0,
    const float* __restrict__ g1, const float* __restrict__ be1,
    float* __restrict__ outf, ushort_t* __restrict__ outb) {
  int row = blockIdx.x;
  int side = row >= ROWS;
  int r = side ? row - ROWS : row;
  int lane = threadIdx.x;
  const float* x = (side ? x1 : x0) + (size_t)r * DD;
  const float* rp = side ? res1 : res0;
  const float* g = side ? g1 : g0;
  const float* be = side ? be1 : be0;
  float v0_ = x[lane], v1_ = x[lane + 64], v2_ = x[lane + 128];
  if (rp != nullptr) {
    const float* rr = rp + (size_t)r * DD;
    v0_ += rr[lane]; v1_ += rr[lane + 64]; v2_ += rr[lane + 128];
  }
  float s = v0_ + v1_ + v2_;
#pragma unroll
  for (int off = 32; off; off >>= 1) s += __shfl_xor(s, off);
  float mu = s * (1.0f / 192.0f);
  float d0 = v0_ - mu, d1 = v1_ - mu, d2 = v2_ - mu;
  float ss = d0 * d0 + d1 * d1 + d2 * d2;
#pragma unroll
  for (int off = 32; off; off >>= 1) ss += __shfl_xor(ss, off);
  float inv = rsqrtf(ss * (1.0f / 192.0f) + 1e-5f);
  float r0, r1, r2;
  if ((side ? v1 : v0)[r]) {
    r0 = d0 * inv * g[lane]       + be[lane];
    r1 = d1 * inv * g[lane + 64]  + be[lane + 64];
    r2 = d2 * inv * g[lane + 128] + be[lane + 128];
  } else {
    r0 = v0_; r1 = v1_; r2 = v2_;
  }
  size_t o = (size_t)row * DD;
  if (outf != nullptr) {
    outf[o + lane] = r0; outf[o + lane + 64] = r1; outf[o + lane + 128] = r2;
  }
  if (outb != nullptr) {
    outb[o + lane] = f2bf(r0); outb[o + lane + 64] = f2bf(r1);
    outb[o + lane + 128] = f2bf(r2);
  }
}

// ---------------------------------------------------------------------------
// Fused chain: y = mln(t + res, ln_oX) -> outf; z = mln(y, fln) -> outb.
// ---------------------------------------------------------------------------
__global__ __launch_bounds__(64) void mln_chain_kernel(
    const float* __restrict__ t,
    const float* __restrict__ res0, const float* __restrict__ res1,
    const int* __restrict__ v0, const int* __restrict__ v1,
    const float* __restrict__ g1a, const float* __restrict__ b1a,
    const float* __restrict__ g1b, const float* __restrict__ b1b,
    const float* __restrict__ g2, const float* __restrict__ b2,
    float* __restrict__ outf, ushort_t* __restrict__ outb) {
  int row = blockIdx.x;
  int side = row >= ROWS;
  int r = side ? row - ROWS : row;
  int lane = threadIdx.x;
  const float* tr = t + (size_t)row * DD;
  const float* rr = (side ? res1 : res0) + (size_t)r * DD;
  const float* g1 = side ? g1b : g1a;
  const float* b1 = side ? b1b : b1a;
  int vld = (side ? v1 : v0)[r];
  float v0_ = tr[lane] + rr[lane];
  float v1_ = tr[lane + 64] + rr[lane + 64];
  float v2_ = tr[lane + 128] + rr[lane + 128];
  float s = v0_ + v1_ + v2_;
#pragma unroll
  for (int off = 32; off; off >>= 1) s += __shfl_xor(s, off);
  float mu = s * (1.0f / 192.0f);
  float d0 = v0_ - mu, d1 = v1_ - mu, d2 = v2_ - mu;
  float ss = d0 * d0 + d1 * d1 + d2 * d2;
#pragma unroll
  for (int off = 32; off; off >>= 1) ss += __shfl_xor(ss, off);
  float inv = rsqrtf(ss * (1.0f / 192.0f) + 1e-5f);
  float y0, y1, y2;
  if (vld) {
    y0 = d0 * inv * g1[lane]       + b1[lane];
    y1 = d1 * inv * g1[lane + 64]  + b1[lane + 64];
    y2 = d2 * inv * g1[lane + 128] + b1[lane + 128];
  } else { y0 = v0_; y1 = v1_; y2 = v2_; }
  size_t o = (size_t)row * DD;
  outf[o + lane] = y0; outf[o + lane + 64] = y1; outf[o + lane + 128] = y2;
  float s2 = y0 + y1 + y2;
#pragma unroll
  for (int off = 32; off; off >>= 1) s2 += __shfl_xor(s2, off);
  float mu2 = s2 * (1.0f / 192.0f);
  float e0 = y0 - mu2, e1 = y1 - mu2, e2 = y2 - mu2;
  float ss2 = e0 * e0 + e1 * e1 + e2 * e2;
#pragma unroll
  for (int off = 32; off; off >>= 1) ss2 += __shfl_xor(ss2, off);
  float inv2 = rsqrtf(ss2 * (1.0f / 192.0f) + 1e-5f);
  float z0, z1, z2;
  if (vld) {
    z0 = e0 * inv2 * g2[lane]       + b2[lane];
    z1 = e1 * inv2 * g2[lane + 64]  + b2[lane + 64];
    z2 = e2 * inv2 * g2[lane + 128] + b2[lane + 128];
  } else { z0 = y0; z1 = y1; z2 = y2; }
  outb[o + lane] = f2bf(z0); outb[o + lane + 64] = f2bf(z1);
  outb[o + lane + 128] = f2bf(z2);
}

// ---------------------------------------------------------------------------
// bf16 MFMA GEMM, 1D grid with XCD swizzle: xcd = id&7 owns a contiguous
// band of row-tiles x ALL col-tiles -> A rows fetched once per XCD.
// ny (=M/128) must be divisible by 8.
// ---------------------------------------------------------------------------
__global__ __launch_bounds__(128) void gemm_mfma_kernel(
    const ushort_t* __restrict__ A, const ushort_t* __restrict__ Wt,
    const float* __restrict__ bias, float* __restrict__ Cf,
    ushort_t* __restrict__ Cb, int M, int N, int K, int gelu, int nx) {
  __shared__ ushort_t As[128 * 40];
  __shared__ ushort_t Bs[64 * 40];
  int id = blockIdx.x;
  int ny8 = (M / 128) >> 3;
  int xcd = id & 7;
  int s = id >> 3;
  int cy = xcd * ny8 + s / nx;
  int cx = s % nx;
  int tid = threadIdx.x;
  int lane = tid & 63;
  int w = tid >> 6;
  int row0 = cy * 128;
  int col0 = cx * 64;
  int l15 = lane & 15;
  int kq = lane >> 4;

  int lr = tid >> 2, lq = tid & 3;
  int lr2 = (tid + 128) >> 2, lq2 = (tid + 128) & 3;
  int nr = tid >> 2, nq = tid & 3;

  f32x4 acc[4][4];
#pragma unroll
  for (int i = 0; i < 4; ++i)
#pragma unroll
    for (int j = 0; j < 4; ++j) acc[i][j] = (f32x4){0.f, 0.f, 0.f, 0.f};

#define LOADAB(AV, BV, K0)                                                   \
  {                                                                          \
    AV[0] = *(const uint4*)(A + (size_t)(row0 + lr) * K + (K0) + lq * 8);    \
    AV[1] = *(const uint4*)(A + (size_t)(row0 + lr2) * K + (K0) + lq2 * 8);  \
    AV[2] = *(const uint4*)(A + (size_t)(row0 + lr + 64) * K + (K0) + lq * 8);   \
    AV[3] = *(const uint4*)(A + (size_t)(row0 + lr2 + 64) * K + (K0) + lq2 * 8); \
    BV[0] = *(const uint4*)(Wt + (size_t)(col0 + nr) * K + (K0) + nq * 8);   \
    BV[1] = *(const uint4*)(Wt + (size_t)(col0 + nr + 32) * K + (K0) + nq * 8);  \
  }

#define STOREAB(AV, BV)                                                      \
  {                                                                          \
    *(uint4*)(&As[lr * 40 + lq * 8]) = AV[0];                                \
    *(uint4*)(&As[lr2 * 40 + lq2 * 8]) = AV[1];                              \
    *(uint4*)(&As[(lr + 64) * 40 + lq * 8]) = AV[2];                         \
    *(uint4*)(&As[(lr2 + 64) * 40 + lq2 * 8]) = AV[3];                       \
    *(uint4*)(&Bs[nr * 40 + nq * 8]) = BV[0];                                \
    *(uint4*)(&Bs[(nr + 32) * 40 + nq * 8]) = BV[1];                         \
  }

#define COMPUTE()                                                            \
  {                                                                          \
    bf16x8 af[4], bf[4];                                                     \
    _Pragma("unroll") for (int mt = 0; mt < 4; ++mt)                         \
      af[mt] = *(const bf16x8*)(&As[(w * 64 + mt * 16 + l15) * 40 + kq * 8]);\
    _Pragma("unroll") for (int nt = 0; nt < 4; ++nt)                         \
      bf[nt] = *(const bf16x8*)(&Bs[(nt * 16 + l15) * 40 + kq * 8]);         \
    _Pragma("unroll") for (int mt = 0; mt < 4; ++mt)                         \
      _Pragma("unroll") for (int nt = 0; nt < 4; ++nt)                       \
        acc[mt][nt] = __builtin_amdgcn_mfma_f32_16x16x32_bf16(               \
            af[mt], bf[nt], acc[mt][nt], 0, 0, 0);                           \
  }

  int iters = K >> 5;
  uint4 avA[4], bvA[2], avB[4], bvB[2];
  LOADAB(avA, bvA, 0)
  for (int it = 0; it < iters; it += 2) {
    __syncthreads();
    STOREAB(avA, bvA)
    __syncthreads();
    if (it + 1 < iters) LOADAB(avB, bvB, (it + 1) << 5)
    COMPUTE()
    __syncthreads();
    STOREAB(avB, bvB)
    __syncthreads();
    if (it + 2 < iters) LOADAB(avA, bvA, (it + 2) << 5)
    COMPUTE()
  }
#undef LOADAB
#undef STOREAB
#undef COMPUTE

  float bcol[4];
#pragma unroll
  for (int nt = 0; nt < 4; ++nt) bcol[nt] = bias[col0 + nt * 16 + l15];
#pragma unroll
  for (int mt = 0; mt < 4; ++mt) {
#pragma unroll
    for (int nt = 0; nt < 4; ++nt) {
      int col = col0 + nt * 16 + l15;
#pragma unroll
      for (int r = 0; r < 4; ++r) {
        int row = row0 + w * 64 + mt * 16 + kq * 4 + r;
        float x = acc[mt][nt][r] + bcol[nt];
        if (gelu) x = 0.5f * x * (1.0f + erff(x * 0.70710678118654752f));
        if (Cf != nullptr) Cf[(size_t)row * N + col] = x;
        else Cb[(size_t)row * N + col] = f2bf(x);
      }
    }
  }
}

// ---------------------------------------------------------------------------
// Fused FFN: C[64,192] = gelu(A[64,192] @ W1t^T + b1) @ W2t^T + b2, per block.
// A tile staged once in LDS; hidden activations only in wave-private LDS
// (no barriers in the hc loop); W1/W2 B-frags read from global (L2-hot).
// Block = 128 threads (2 waves); wave w owns rows w*32..w*32+31.
// ---------------------------------------------------------------------------
__global__ __launch_bounds__(128, 2) void ffn_fused_kernel(
    const ushort_t* __restrict__ A, const ushort_t* __restrict__ W1t,
    const float* __restrict__ bias1, const ushort_t* __restrict__ W2t,
    const float* __restrict__ bias2, float* __restrict__ C) {
  __shared__ ushort_t As[64 * 200];      // [row][k], pad 192->200
  __shared__ ushort_t Hs[2][32 * 72];    // per-wave hidden chunk [row][k]
  int tid = threadIdx.x;
  int w = tid >> 6;
  int lane = tid & 63;
  int l15 = lane & 15;
  int kq = lane >> 4;
  int row0 = blockIdx.x * 64;

  // stage A: 64 rows x 24 uint4 = 1536 / 128 threads = 12 each
#pragma unroll
  for (int i = 0; i < 12; ++i) {
    int idx = tid + i * 128;
    int r = idx / 24, c = (idx % 24) * 8;
    *(uint4*)(&As[r * 200 + c]) = *(const uint4*)(A + (size_t)(row0 + r) * DD + c);
  }
  __syncthreads();

  f32x4 Cacc[2][12];
#pragma unroll
  for (int qs = 0; qs < 2; ++qs)
#pragma unroll
    for (int nt = 0; nt < 12; ++nt) Cacc[qs][nt] = (f32x4){0.f, 0.f, 0.f, 0.f};

  for (int hc = 0; hc < 12; ++hc) {
    // --- H = A @ W1t[hc*64..+64]^T ---
    f32x4 Hacc[2][4];
#pragma unroll
    for (int qs = 0; qs < 2; ++qs)
#pragma unroll
      for (int nt = 0; nt < 4; ++nt) Hacc[qs][nt] = (f32x4){0.f, 0.f, 0.f, 0.f};
#pragma unroll
    for (int kk = 0; kk < 6; ++kk) {
      bf16x8 af[2], bf[4];
#pragma unroll
      for (int qs = 0; qs < 2; ++qs)
        af[qs] = *(const bf16x8*)(&As[(w * 32 + qs * 16 + l15) * 200 + kk * 32 + kq * 8]);
#pragma unroll
      for (int nt = 0; nt < 4; ++nt) {
        U4BF8 t;
        t.u = *(const uint4*)(W1t + (size_t)(hc * 64 + nt * 16 + l15) * DD + kk * 32 + kq * 8);
        bf[nt] = t.b;
      }
#pragma unroll
      for (int qs = 0; qs < 2; ++qs)
#pragma unroll
        for (int nt = 0; nt < 4; ++nt)
          Hacc[qs][nt] = __builtin_amdgcn_mfma_f32_16x16x32_bf16(
              af[qs], bf[nt], Hacc[qs][nt], 0, 0, 0);
    }
    // --- gelu + bias -> bf16 -> wave-private LDS ---
#pragma unroll
    for (int qs = 0; qs < 2; ++qs)
#pragma unroll
      for (int nt = 0; nt < 4; ++nt) {
        float bb = bias1[hc * 64 + nt * 16 + l15];
#pragma unroll
        for (int r = 0; r < 4; ++r) {
          float x = Hacc[qs][nt][r] + bb;
          x = 0.5f * x * (1.0f + erff(x * 0.70710678118654752f));
          Hs[w][(qs * 16 + kq * 4 + r) * 72 + nt * 16 + l15] = f2bf(x);
        }
      }
    // --- C += H @ W2t[:, hc*64..+64]^T (same-wave LDS: no barrier) ---
#pragma unroll
    for (int kk2 = 0; kk2 < 2; ++kk2) {
      bf16x8 hf[2];
#pragma unroll
      for (int qs = 0; qs < 2; ++qs)
        hf[qs] = *(const bf16x8*)(&Hs[w][(qs * 16 + l15) * 72 + kk2 * 32 + kq * 8]);
#pragma unroll
      for (int nt = 0; nt < 12; ++nt) {
        U4BF8 t;
        t.u = *(const uint4*)(W2t + (size_t)(nt * 16 + l15) * HID + hc * 64 + kk2 * 32 + kq * 8);
#pragma unroll
        for (int qs = 0; qs < 2; ++qs)
          Cacc[qs][nt] = __builtin_amdgcn_mfma_f32_16x16x32_bf16(
              hf[qs], t.b, Cacc[qs][nt], 0, 0, 0);
      }
    }
  }

  // epilogue
#pragma unroll
  for (int qs = 0; qs < 2; ++qs)
#pragma unroll
    for (int nt = 0; nt < 12; ++nt) {
      int col = nt * 16 + l15;
      float bb = bias2[col];
#pragma unroll
      for (int r = 0; r < 4; ++r) {
        int row = row0 + w * 32 + qs * 16 + kq * 4 + r;
        C[(size_t)row * DD + col] = Cacc[qs][nt][r] + bb;
      }
    }
}

// ---------------------------------------------------------------------------
// MFMA flash attention (validated R6/R7): both sides, no online max,
// XCD swizzle groups q-tiles of one (b,h,side).
// ---------------------------------------------------------------------------
__global__ __launch_bounds__(256) void attn_mfma_kernel(
    const ushort_t* __restrict__ QKV,
    const int* __restrict__ valid_a, const int* __restrict__ valid_b,
    ushort_t* __restrict__ out) {
  int i = blockIdx.x;
  int gid = ((i >> 5) << 3) | (i & 7);
  int qt = (i >> 3) & 3;
  int side = gid >= BB * HH;
  int grem = side ? gid - BB * HH : gid;
  int h = grem % HH;
  int batch = grem / HH;
  int tid = threadIdx.x;
  int w = tid >> 6;
  int lane = tid & 63;
  int l15 = lane & 15;
  int kq = lane >> 4;

  const int* validq = side ? valid_b : valid_a;
  const int* validk = side ? valid_a : valid_b;
  size_t qrow0  = (size_t)side * ROWS + (size_t)batch * LL;
  size_t kvrow0 = (size_t)(1 - side) * ROWS + (size_t)batch * LL;

  __shared__ ushort_t VsT[32 * 72];
  __shared__ ushort_t Ps[4][32 * 72];

  int qbase = qt * 128 + w * 32;

  U4BF8 qfrag[2];
#pragma unroll
  for (int qs = 0; qs < 2; ++qs)
    qfrag[qs].u = *(const uint4*)(QKV + (qrow0 + qbase + qs * 16 + l15) * 576 +
                                  h * DKK + kq * 8);

  int vq[2][4];
#pragma unroll
  for (int qs = 0; qs < 2; ++qs)
#pragma unroll
    for (int r = 0; r < 4; ++r)
      vq[qs][r] = validq[batch * LL + qbase + qs * 16 + kq * 4 + r];

  float lsum[2][4];
  f32x4 Oacc[2][2];
#pragma unroll
  for (int qs = 0; qs < 2; ++qs) {
#pragma unroll
    for (int r = 0; r < 4; ++r) lsum[qs][r] = 0.0f;
#pragma unroll
    for (int ds = 0; ds < 2; ++ds) Oacc[qs][ds] = (f32x4){0.f, 0.f, 0.f, 0.f};
  }

  for (int c = 0; c < LL; c += 64) {
    __syncthreads();
    uint4 vv = *(const uint4*)(QKV + (kvrow0 + c + lane) * 576 +
                               384 + h * DKK + w * 8);
    uint_t uu[4] = {vv.x, vv.y, vv.z, vv.w};
#pragma unroll
    for (int j = 0; j < 4; ++j) {
      VsT[(w * 8 + 2 * j) * 72 + lane]     = (ushort_t)(uu[j] & 0xffffu);
      VsT[(w * 8 + 2 * j + 1) * 72 + lane] = (ushort_t)(uu[j] >> 16);
    }
    __syncthreads();

    f32x4 S[2][4];
    int vk[4];
#pragma unroll
    for (int ks = 0; ks < 4; ++ks) {
      U4BF8 kf;
      kf.u = *(const uint4*)(QKV + (kvrow0 + c + ks * 16 + l15) * 576 +
                             192 + h * DKK + kq * 8);
      vk[ks] = validk[batch * LL + c + ks * 16 + l15];
#pragma unroll
      for (int qs = 0; qs < 2; ++qs) {
        f32x4 z = (f32x4){0.f, 0.f, 0.f, 0.f};
        S[qs][ks] = __builtin_amdgcn_mfma_f32_16x16x32_bf16(
            qfrag[qs].b, kf.b, z, 0, 0, 0);
      }
    }

#pragma unroll
    for (int qs = 0; qs < 2; ++qs)
#pragma unroll
      for (int ks = 0; ks < 4; ++ks)
#pragma unroll
        for (int r = 0; r < 4; ++r) {
          float x = (vq[qs][r] && vk[ks]) ? S[qs][ks][r] * SCALE_ATT : MASKED_S;
          float p = __expf(x);
          ushort_t pb = f2bf(p);
          lsum[qs][r] += bf2f(pb);
          Ps[w][(qs * 16 + kq * 4 + r) * 72 + ks * 16 + l15] = pb;
        }

#pragma unroll
    for (int kh = 0; kh < 2; ++kh) {
      bf16x8 pf[2], vf[2];
#pragma unroll
      for (int qs = 0; qs < 2; ++qs)
        pf[qs] = *(const bf16x8*)(&Ps[w][(qs * 16 + l15) * 72 + kh * 32 + kq * 8]);
#pragma unroll
      for (int ds = 0; ds < 2; ++ds)
        vf[ds] = *(const bf16x8*)(&VsT[(ds * 16 + l15) * 72 + kh * 32 + kq * 8]);
#pragma unroll
      for (int qs = 0; qs < 2; ++qs)
#pragma unroll
        for (int ds = 0; ds < 2; ++ds)
          Oacc[qs][ds] = __builtin_amdgcn_mfma_f32_16x16x32_bf16(
              pf[qs], vf[ds], Oacc[qs][ds], 0, 0, 0);
    }
  }

#pragma unroll
  for (int qs = 0; qs < 2; ++qs)
#pragma unroll
    for (int r = 0; r < 4; ++r) {
      float sm = lsum[qs][r];
#pragma unroll
      for (int off = 1; off < 16; off <<= 1) sm += __shfl_xor(sm, off);
      lsum[qs][r] = sm;
    }

#pragma unroll
  for (int qs = 0; qs < 2; ++qs)
#pragma unroll
    for (int ds = 0; ds < 2; ++ds)
#pragma unroll
      for (int r = 0; r < 4; ++r) {
        int q = qbase + qs * 16 + kq * 4 + r;
        out[(qrow0 + q) * DD + h * DKK + ds * 16 + l15] =
            f2bf(Oacc[qs][ds][r] / lsum[qs][r]);
      }
}

// ---------------------------------------------------------------------------
extern "C" void kernel_launch(void* const* d_in, const int* in_sizes, int n_in,
                              void* d_out, int out_size, void* d_ws, size_t ws_size,
                              hipStream_t stream) {
  const float* x_a = (const float*)d_in[0];
  const float* x_b = (const float*)d_in[1];
  const int* valid_a = (const int*)d_in[2];
  const int* valid_b = (const int*)d_in[3];
  const float* ln_a_g = (const float*)d_in[4];
  const float* ln_a_b = (const float*)d_in[5];
  const float* ln_b_g = (const float*)d_in[6];
  const float* ln_b_b = (const float*)d_in[7];
  const float* ln_oa_g = (const float*)d_in[8];
  const float* ln_oa_b = (const float*)d_in[9];
  const float* ln_ob_g = (const float*)d_in[10];
  const float* ln_ob_b = (const float*)d_in[11];
  const float* wq = (const float*)d_in[12];
  const float* bq = (const float*)d_in[13];
  const float* wk = (const float*)d_in[14];
  const float* bk = (const float*)d_in[15];
  const float* wv = (const float*)d_in[16];
  const float* bv = (const float*)d_in[17];
  const float* wo = (const float*)d_in[18];
  const float* bo = (const float*)d_in[19];
  const float* fln_g = (const float*)d_in[20];
  const float* fln_b = (const float*)d_in[21];
  const float* flno_g = (const float*)d_in[22];
  const float* flno_b = (const float*)d_in[23];
  const float* w1 = (const float*)d_in[24];
  const float* b1 = (const float*)d_in[25];
  const float* w2 = (const float*)d_in[26];
  const float* b2 = (const float*)d_in[27];

  // Workspace: weights [0, 887040); lnFull/attO bf16 [2R,192] at 887040;
  // QKV bf16 [2R,576] at 19761408; tmp fp32 [2R,192] at 76384512. ~114 MB.
  char* wsb = (char*)d_ws;
  ushort_t* Wqkv = (ushort_t*)wsb;
  ushort_t* Wo_t = Wqkv + 110592;
  ushort_t* W1_t = Wo_t + 36864;
  ushort_t* W2_t = W1_t + 147456;
  float*    bqkv = (float*)(W2_t + 147456);
  ushort_t* lnFull = (ushort_t*)(wsb + 887040);
  ushort_t* attO   = lnFull;
  ushort_t* QKV = (ushort_t*)(wsb + 19761408);
  float* tmp = (float*)(wsb + 76384512);

  float* out_a = (float*)d_out;   // [2R,192] fp32 contiguous

  dim3 b64(64), b128(128), b256(256);
  dim3 gMln(2 * ROWS);
  dim3 gQKV(9 * (2 * ROWS / 128));              // 1D swizzled: nx=9
  dim3 gO(3 * (2 * ROWS / 128));                // nx=3
  dim3 gAttn(BB * HH * 4 * 2);                  // 2304
  dim3 gFFN(2 * ROWS / 64);                     // 768

  hipLaunchKernelGGL(pack_kernel, dim3(1731), b256, 0, stream,
                     wq, wk, wv, wo, w1, w2, bq, bk, bv,
                     Wqkv, Wo_t, W1_t, W2_t, bqkv);

  // 1. pre-LN both sides -> lnFull bf16
  hipLaunchKernelGGL(mln2_kernel, gMln, b64, 0, stream,
                     x_a, x_b, (const float*)nullptr, (const float*)nullptr,
                     valid_a, valid_b, ln_a_g, ln_a_b, ln_b_g, ln_b_b,
                     (float*)nullptr, lnFull);

  // 2. fused QKV, both sides
  hipLaunchKernelGGL(gemm_mfma_kernel, gQKV, b128, 0, stream,
                     lnFull, Wqkv, bqkv, (float*)nullptr, QKV,
                     2 * ROWS, 576, DD, 0, 9);

  // 3. attention, both sides
  hipLaunchKernelGGL(attn_mfma_kernel, gAttn, b256, 0, stream,
                     QKV, valid_a, valid_b, attO);

  // 4. O-projection, both sides -> tmp fp32
  hipLaunchKernelGGL(gemm_mfma_kernel, gO, b128, 0, stream,
                     attO, Wo_t, bo, tmp, (ushort_t*)nullptr,
                     2 * ROWS, DD, DD, 0, 3);

  // 5+6. fused residual-LN -> d_out, FFN pre-LN -> lnFull bf16
  hipLaunchKernelGGL(mln_chain_kernel, gMln, b64, 0, stream,
                     tmp, x_a, x_b, valid_a, valid_b,
                     ln_oa_g, ln_oa_b, ln_ob_g, ln_ob_b, fln_g, fln_b,
                     out_a, lnFull);

  // 7. fused FFN (no hidden round-trip) -> tmp fp32
  hipLaunchKernelGGL(ffn_fused_kernel, gFFN, b128, 0, stream,
                     lnFull, W1_t, b1, W2_t, b2, tmp);

  // 8. FFN residual + LN -> d_out
  hipLaunchKernelGGL(mln2_kernel, gMln, b64, 0, stream,
                     tmp, tmp + BLD, out_a, out_a + BLD,
                     valid_a, valid_b, flno_g, flno_b, flno_g, flno_b,
                     out_a, (ushort_t*)nullptr);
}